// Round 1
// 1159.311 us; speedup vs baseline: 1.0469x; 1.0469x over previous
//
#include <hip/hip_runtime.h>

// ---------------------------------------------------------------------------
// Qwen2 attention forward: QKV proj + RoPE + causal GQA attention + O proj
// B=2 S=2048 HIDDEN=3584 NH=28 NKV=4 D=128
// ---------------------------------------------------------------------------

typedef __bf16 bf16x8 __attribute__((ext_vector_type(8)));
typedef float floatx4 __attribute__((ext_vector_type(4)));
typedef unsigned short ushort8v __attribute__((ext_vector_type(8)));
typedef unsigned short ushort4v __attribute__((ext_vector_type(4)));

__device__ __forceinline__ unsigned short f2bf(float f) {
    union { float f; unsigned int u; } v; v.f = f;
    return (unsigned short)((v.u + 0x7fffu + ((v.u >> 16) & 1u)) >> 16);
}
__device__ __forceinline__ float bf2f(unsigned short b) {
    union { unsigned int u; float f; } v; v.u = ((unsigned int)b) << 16;
    return v.f;
}
__device__ __forceinline__ floatx4 mfma16(bf16x8 a, bf16x8 b, floatx4 c) {
    return __builtin_amdgcn_mfma_f32_16x16x32_bf16(a, b, c, 0, 0, 0);
}
__device__ __forceinline__ bf16x8 ld8(const unsigned short* p) {
    ushort8v t = *(const ushort8v*)p;
    return __builtin_bit_cast(bf16x8, t);
}

// async global->LDS, 16B per lane; LDS dest = wave-uniform base + lane*16
#define GLL16(g, l) __builtin_amdgcn_global_load_lds( \
    (const __attribute__((address_space(1))) void*)(g), \
    (__attribute__((address_space(3))) void*)(l), 16, 0, 0)

// ---------------------------------------------------------------------------
// fp32 -> bf16 bulk convert of 5 arrays (vec4 granularity)
// ---------------------------------------------------------------------------
__global__ __launch_bounds__(256) void convert5(
    const float* __restrict__ s0, const float* __restrict__ s1,
    const float* __restrict__ s2, const float* __restrict__ s3,
    const float* __restrict__ s4,
    unsigned short* __restrict__ d0, unsigned short* __restrict__ d1,
    unsigned short* __restrict__ d2, unsigned short* __restrict__ d3,
    unsigned short* __restrict__ d4,
    int n0, int n1, int n2, int n3, int n4)
{
    int total = n0 + n1 + n2 + n3 + n4;
    for (int i = blockIdx.x * blockDim.x + threadIdx.x; i < total;
         i += gridDim.x * blockDim.x) {
        const float* s; unsigned short* d; int j = i;
        if (j < n0)      { s = s0; d = d0; }
        else { j -= n0; if (j < n1) { s = s1; d = d1; }
        else { j -= n1; if (j < n2) { s = s2; d = d2; }
        else { j -= n2; if (j < n3) { s = s3; d = d3; }
        else { j -= n3;   s = s4; d = d4; } } } }
        float4 v = ((const float4*)s)[j];
        ushort4v o;
        o[0] = f2bf(v.x); o[1] = f2bf(v.y); o[2] = f2bf(v.z); o[3] = f2bf(v.w);
        ((ushort4v*)d)[j] = o;
    }
}

// ---------------------------------------------------------------------------
// all-bf16 NT GEMM: C[m][n] = sum_k A[m][k]*B[n][k] (+bias[n])
// 128x128 tile, BK=32, global_load_lds staging into XOR-swizzled LDS.
// ---------------------------------------------------------------------------
template<bool HAS_BIAS, bool OUT_BF16>
__global__ __launch_bounds__(256) void gemm_bb(
    const unsigned short* __restrict__ A, const unsigned short* __restrict__ B,
    const float* __restrict__ bias, void* __restrict__ C,
    int K, int ldc)
{
    __shared__ unsigned short As[128 * 32];   // row stride 32 ushorts, swizzled
    __shared__ unsigned short Bs[128 * 32];

    const int tid = threadIdx.x, lane = tid & 63, w = tid >> 6;
    const int quad = lane >> 4, l16 = lane & 15;
    const int m0 = blockIdx.x * 128, n0 = blockIdx.y * 128;
    const int wm = (w & 1) * 64, wn = (w >> 1) * 64;

    floatx4 acc[4][4] = {};

    for (int k0 = 0; k0 < K; k0 += 32) {
        __syncthreads();
        #pragma unroll
        for (int p = 0; p < 2; ++p) {
            int c = (w * 2 + p) * 64 + lane;      // chunk 0..511
            int row = c >> 2, sp = c & 3;
            int slog = sp ^ ((row ^ (row >> 2)) & 3);
            GLL16(A + (size_t)(m0 + row) * K + k0 + slog * 8,
                  (unsigned short*)As + (w * 2 + p) * 512);
            GLL16(B + (size_t)(n0 + row) * K + k0 + slog * 8,
                  (unsigned short*)Bs + (w * 2 + p) * 512);
        }
        __syncthreads();
        bf16x8 af[4], bf[4];
        #pragma unroll
        for (int i = 0; i < 4; ++i) {
            int row = wm + i * 16 + l16;
            int sp = quad ^ ((row ^ (row >> 2)) & 3);
            af[i] = ld8((unsigned short*)As + row * 32 + sp * 8);
        }
        #pragma unroll
        for (int j = 0; j < 4; ++j) {
            int row = wn + j * 16 + l16;
            int sp = quad ^ ((row ^ (row >> 2)) & 3);
            bf[j] = ld8((unsigned short*)Bs + row * 32 + sp * 8);
        }
        #pragma unroll
        for (int i = 0; i < 4; ++i)
            #pragma unroll
            for (int j = 0; j < 4; ++j)
                acc[i][j] = mfma16(af[i], bf[j], acc[i][j]);
    }

    #pragma unroll
    for (int j = 0; j < 4; ++j) {
        int col = n0 + wn + j * 16 + l16;
        float bb = HAS_BIAS ? bias[col] : 0.0f;
        #pragma unroll
        for (int i = 0; i < 4; ++i) {
            int row = m0 + wm + i * 16 + quad * 4;
            #pragma unroll
            for (int r = 0; r < 4; ++r) {
                float v = acc[i][j][r] + bb;
                if (OUT_BF16)
                    ((unsigned short*)C)[(size_t)(row + r) * ldc + col] = f2bf(v);
                else
                    ((float*)C)[(size_t)(row + r) * ldc + col] = v;
            }
        }
    }
}

// ---------------------------------------------------------------------------
// v1 fp32-staging GEMM (fallback path when workspace is small)
// ---------------------------------------------------------------------------
template<bool A_BF16, bool HAS_BIAS, bool OUT_BF16>
__global__ __launch_bounds__(256) void gemm_nt(
    const void* __restrict__ Ap, const float* __restrict__ Bp,
    const float* __restrict__ bias, void* __restrict__ Cp,
    int K, int ldc)
{
    __shared__ unsigned short As[128][40];
    __shared__ unsigned short Bs[128][40];

    const int tid = threadIdx.x, lane = tid & 63, w = tid >> 6;
    const int quad = lane >> 4, l16 = lane & 15;
    const int m0 = blockIdx.x * 128, n0 = blockIdx.y * 128;
    const int wm = (w & 1) * 64, wn = (w >> 1) * 64;

    floatx4 acc[4][4] = {};

    for (int k0 = 0; k0 < K; k0 += 32) {
        __syncthreads();
        if (A_BF16) {
            const unsigned short* Ab = (const unsigned short*)Ap;
            #pragma unroll
            for (int p = 0; p < 2; ++p) {
                int idx = tid + p * 256;
                int row = idx >> 2, seg = idx & 3;
                ushort8v v = *(const ushort8v*)(Ab + (size_t)(m0 + row) * K + k0 + seg * 8);
                *(ushort8v*)&As[row][seg * 8] = v;
            }
        } else {
            const float* Af = (const float*)Ap;
            #pragma unroll
            for (int p = 0; p < 4; ++p) {
                int idx = tid + p * 256;
                int row = idx >> 3, seg = idx & 7;
                const float4 v = *(const float4*)(Af + (size_t)(m0 + row) * K + k0 + seg * 4);
                ushort4v b;
                b[0] = f2bf(v.x); b[1] = f2bf(v.y); b[2] = f2bf(v.z); b[3] = f2bf(v.w);
                *(ushort4v*)&As[row][seg * 4] = b;
            }
        }
        #pragma unroll
        for (int p = 0; p < 4; ++p) {
            int idx = tid + p * 256;
            int row = idx >> 3, seg = idx & 7;
            const float4 v = *(const float4*)(Bp + (size_t)(n0 + row) * K + k0 + seg * 4);
            ushort4v b;
            b[0] = f2bf(v.x); b[1] = f2bf(v.y); b[2] = f2bf(v.z); b[3] = f2bf(v.w);
            *(ushort4v*)&Bs[row][seg * 4] = b;
        }
        __syncthreads();
        bf16x8 af[4], bv[4];
        #pragma unroll
        for (int i = 0; i < 4; ++i) af[i] = ld8(&As[wm + i * 16 + l16][quad * 8]);
        #pragma unroll
        for (int j = 0; j < 4; ++j) bv[j] = ld8(&Bs[wn + j * 16 + l16][quad * 8]);
        #pragma unroll
        for (int i = 0; i < 4; ++i)
            #pragma unroll
            for (int j = 0; j < 4; ++j)
                acc[i][j] = mfma16(af[i], bv[j], acc[i][j]);
    }

    #pragma unroll
    for (int j = 0; j < 4; ++j) {
        int col = n0 + wn + j * 16 + l16;
        float bb = HAS_BIAS ? bias[col] : 0.0f;
        #pragma unroll
        for (int i = 0; i < 4; ++i) {
            int row = m0 + wm + i * 16 + quad * 4;
            #pragma unroll
            for (int r = 0; r < 4; ++r) {
                float v = acc[i][j][r] + bb;
                if (OUT_BF16)
                    ((unsigned short*)Cp)[(size_t)(row + r) * ldc + col] = f2bf(v);
                else
                    ((float*)Cp)[(size_t)(row + r) * ldc + col] = v;
            }
        }
    }
}

// ---------------------------------------------------------------------------
// RoPE in place: one block per token, 32 head-slices (28 q + 4 k)
// ---------------------------------------------------------------------------
__global__ __launch_bounds__(256) void rope2(
    unsigned short* __restrict__ Q, unsigned short* __restrict__ K,
    const float* __restrict__ cosp, const float* __restrict__ sinp)
{
    const int tok = blockIdx.x, tid = threadIdx.x;
    __shared__ float cs[128], ss[128];
    if (tid < 128) {
        cs[tid] = cosp[(size_t)tok * 128 + tid];
        ss[tid] = sinp[(size_t)tok * 128 + tid];
    }
    __syncthreads();

    ushort8v x[2], x2[2];
    unsigned short* bases[2];
    int segs[2];
    #pragma unroll
    for (int p = 0; p < 2; ++p) {
        int chunk = tid + p * 256;              // 0..511
        int hh = chunk >> 4, seg = chunk & 15;
        unsigned short* base = (hh < 28)
            ? Q + (size_t)tok * 3584 + hh * 128
            : K + (size_t)tok * 512 + (hh - 28) * 128;
        bases[p] = base; segs[p] = seg;
        x[p]  = *(const ushort8v*)(base + seg * 8);
        x2[p] = *(const ushort8v*)(base + (seg ^ 8) * 8);
    }
    __syncthreads();   // all reads complete before any thread writes
    #pragma unroll
    for (int p = 0; p < 2; ++p) {
        int seg = segs[p];
        ushort8v y;
        #pragma unroll
        for (int j = 0; j < 8; ++j) {
            int d = seg * 8 + j;
            float xv = bf2f(x[p][j]);
            float rv = bf2f(x2[p][j]);
            float rot = (seg < 8) ? -rv : rv;
            y[j] = f2bf(xv * cs[d] + rot * ss[d]);
        }
        *(ushort8v*)(bases[p] + seg * 8) = y;
    }
}

// ---------------------------------------------------------------------------
// V transpose: vb[4096 tok][512 gd] -> vt[512 gd][4096 tok]
// ---------------------------------------------------------------------------
__global__ __launch_bounds__(256) void transpose_v(
    const unsigned short* __restrict__ vb, unsigned short* __restrict__ vt)
{
    __shared__ unsigned short Ts[64][68];
    const int t0 = blockIdx.x * 64, c0 = blockIdx.y * 64;
    const int tid = threadIdx.x;
    #pragma unroll
    for (int it = 0; it < 4; ++it) {
        int idx = tid + it * 256;
        int row = idx >> 4, seg = idx & 15;
        *(ushort4v*)&Ts[row][seg * 4] =
            *(const ushort4v*)(vb + (size_t)(t0 + row) * 512 + c0 + seg * 4);
    }
    __syncthreads();
    #pragma unroll
    for (int it = 0; it < 4; ++it) {
        int idx = tid + it * 256;
        int gd = idx >> 4, seg = idx & 15;
        ushort4v y;
        #pragma unroll
        for (int j = 0; j < 4; ++j) y[j] = Ts[seg * 4 + j][gd];
        *(ushort4v*)(vt + (size_t)(c0 + gd) * 4096 + t0 + seg * 4) = y;
    }
}

// ---------------------------------------------------------------------------
// Flash attention v3: barrier-free. Q-frags in regs; K and V^T B-frags read
// directly from global (K/V slices are L2-resident: 512KB each per (b,kvh)).
// Per-wave-private P transpose via LDS (no cross-wave sharing -> no syncs).
// Grid: 1D 1792, slice-pinned to XCDs (bid%8 -> one (b,kvh) KV slice per
// XCD L2) with LPT (qt descending) inside each slice.
// ---------------------------------------------------------------------------
__global__ __launch_bounds__(256) void attn3(
    const unsigned short* __restrict__ Q, const unsigned short* __restrict__ Kb,
    const unsigned short* __restrict__ Vt, unsigned short* __restrict__ O)
{
    const int bid   = blockIdx.x;
    const int slice = bid & 7;          // -> XCD via round-robin dispatch
    const int b     = slice & 1;
    const int kvh   = slice >> 1;
    const int j     = bid >> 3;         // 0..223 within slice
    const int qt    = 31 - (j / 7);     // LPT: heaviest q-tiles first
    const int h     = kvh * 7 + (j % 7);

    const int tid = threadIdx.x, lane = tid & 63, w = tid >> 6;
    const int quad = lane >> 4, l16 = lane & 15;

    __shared__ unsigned short Ps[64][72];   // per-wave-private rows [w*16, w*16+16)

    // Q fragments in registers (A-layout), held for whole kernel
    bf16x8 aq[4];
    {
        const unsigned short* qp =
            Q + (size_t)(b * 2048 + qt * 64 + w * 16 + l16) * 3584 + h * 128 + quad * 8;
        #pragma unroll
        for (int ks = 0; ks < 4; ++ks) aq[ks] = ld8(qp + ks * 32);
    }

    const unsigned short* vbase = Vt + (size_t)kvh * 128 * 4096 + b * 2048;
    const unsigned short* kbase = Kb + (size_t)(b * 2048) * 512 + kvh * 128 + quad * 8;

    floatx4 o[8] = {};
    float mrow[4] = {-1e30f, -1e30f, -1e30f, -1e30f};
    float lrow[4] = {0.f, 0.f, 0.f, 0.f};
    // fold 1/sqrt(128) and log2(e) into one exp2-domain constant
    const float cexp = 0.08838834764831845f * 1.4426950408889634f;

    for (int kt = 0; kt <= qt; ++kt) {
        // ---- S = Q K^T (K B-frags straight from global, raw domain) ----
        floatx4 s[4] = {};
        const unsigned short* kp = kbase + (size_t)(kt * 64) * 512;
        #pragma unroll
        for (int ks = 0; ks < 4; ++ks) {
            bf16x8 kf[4];
            #pragma unroll
            for (int n4 = 0; n4 < 4; ++n4)
                kf[n4] = ld8(kp + (size_t)(n4 * 16 + l16) * 512 + ks * 32);
            #pragma unroll
            for (int n4 = 0; n4 < 4; ++n4)
                s[n4] = mfma16(aq[ks], kf[n4], s[n4]);
        }

        // ---- online softmax (raw domain; scale folded into exp2 arg) ----
        const bool diag = (kt == qt);
        #pragma unroll
        for (int r = 0; r < 4; ++r) {
            int qg = qt * 64 + w * 16 + quad * 4 + r;
            float v0 = s[0][r];
            float v1 = s[1][r];
            float v2 = s[2][r];
            float v3 = s[3][r];
            if (diag) {
                int kg = kt * 64 + l16;
                if (kg      > qg) v0 = -1e30f;
                if (kg + 16 > qg) v1 = -1e30f;
                if (kg + 32 > qg) v2 = -1e30f;
                if (kg + 48 > qg) v3 = -1e30f;
            }
            float mx = fmaxf(fmaxf(v0, v1), fmaxf(v2, v3));
            #pragma unroll
            for (int off = 1; off < 16; off <<= 1)
                mx = fmaxf(mx, __shfl_xor(mx, off, 64));
            float mnew  = fmaxf(mrow[r], mx);
            float t     = mnew * cexp;
            float alpha = __builtin_amdgcn_exp2f(mrow[r] * cexp - t);
            float p0 = __builtin_amdgcn_exp2f(fmaf(v0, cexp, -t));
            float p1 = __builtin_amdgcn_exp2f(fmaf(v1, cexp, -t));
            float p2 = __builtin_amdgcn_exp2f(fmaf(v2, cexp, -t));
            float p3 = __builtin_amdgcn_exp2f(fmaf(v3, cexp, -t));
            float rs = p0 + p1 + p2 + p3;
            #pragma unroll
            for (int off = 1; off < 16; off <<= 1)
                rs += __shfl_xor(rs, off, 64);
            lrow[r] = lrow[r] * alpha + rs;
            mrow[r] = mnew;
            #pragma unroll
            for (int d4 = 0; d4 < 8; ++d4) o[d4][r] *= alpha;
            int prow = w * 16 + quad * 4 + r;
            Ps[prow][ 0 + l16] = f2bf(p0);
            Ps[prow][16 + l16] = f2bf(p1);
            Ps[prow][32 + l16] = f2bf(p2);
            Ps[prow][48 + l16] = f2bf(p3);
        }

        // ---- O += P V (V^T B-frags straight from global) ----
        #pragma unroll
        for (int ks2 = 0; ks2 < 2; ++ks2) {
            bf16x8 ap = ld8(&Ps[w * 16 + l16][ks2 * 32 + quad * 8]);
            const unsigned short* vp = vbase + kt * 64 + ks2 * 32 + quad * 8;
            #pragma unroll
            for (int d4 = 0; d4 < 8; ++d4) {
                bf16x8 bv = ld8(vp + (size_t)(d4 * 16 + l16) * 4096);
                o[d4] = mfma16(ap, bv, o[d4]);
            }
        }
    }

    #pragma unroll
    for (int d4 = 0; d4 < 8; ++d4) {
        int col = h * 128 + d4 * 16 + l16;
        #pragma unroll
        for (int r = 0; r < 4; ++r) {
            int row = b * 2048 + qt * 64 + w * 16 + quad * 4 + r;
            O[(size_t)row * 3584 + col] = f2bf(o[d4][r] / lrow[r]);
        }
    }
}

// ---------------------------------------------------------------------------
extern "C" void kernel_launch(void* const* d_in, const int* in_sizes, int n_in,
                              void* d_out, int out_size, void* d_ws, size_t ws_size,
                              hipStream_t stream)
{
    (void)in_sizes; (void)n_in; (void)out_size;
    const float* hs   = (const float*)d_in[0];
    const float* cosp = (const float*)d_in[1];
    const float* sinp = (const float*)d_in[2];
    const float* Wq   = (const float*)d_in[3];
    const float* bq   = (const float*)d_in[4];
    const float* Wk   = (const float*)d_in[5];
    const float* bk   = (const float*)d_in[6];
    const float* Wv   = (const float*)d_in[7];
    const float* bv   = (const float*)d_in[8];
    const float* Wo   = (const float*)d_in[9];
    float* out = (float*)d_out;

    const size_t NHS = 14680064;   // 4096*3584
    const size_t NWQ = 12845056;   // 3584*3584
    const size_t NWKV = 1835008;   // 512*3584
    const size_t NWO = 12845056;
    const size_t NQ  = 14680064;
    const size_t NKV = 2097152;    // 4096*512

    const size_t need = 2 * (NHS + NQ + NQ + 3 * NKV + NWQ + 2 * NWKV + NWO);
    dim3 blk(256);

    if (ws_size >= need) {
        unsigned short* hb  = (unsigned short*)d_ws;
        unsigned short* qb  = hb + NHS;
        unsigned short* ab  = qb + NQ;
        unsigned short* kb  = ab + NQ;
        unsigned short* vb  = kb + NKV;
        unsigned short* vt  = vb + NKV;
        unsigned short* Wqb = vt + NKV;
        unsigned short* Wkb = Wqb + NWQ;
        unsigned short* Wvb = Wkb + NWKV;
        unsigned short* Wob = Wvb + NWKV;

        convert5<<<dim3(1024), blk, 0, stream>>>(
            hs, Wq, Wk, Wv, Wo, hb, Wqb, Wkb, Wvb, Wob,
            (int)(NHS / 4), (int)(NWQ / 4), (int)(NWKV / 4), (int)(NWKV / 4), (int)(NWO / 4));

        gemm_bb<true, true><<<dim3(32, 28), blk, 0, stream>>>(hb, Wqb, bq, qb, 3584, 3584);
        gemm_bb<true, true><<<dim3(32, 4),  blk, 0, stream>>>(hb, Wkb, bk, kb, 3584, 512);
        gemm_bb<true, true><<<dim3(32, 4),  blk, 0, stream>>>(hb, Wvb, bv, vb, 3584, 512);
        rope2<<<dim3(4096), blk, 0, stream>>>(qb, kb, cosp, sinp);
        transpose_v<<<dim3(64, 8), blk, 0, stream>>>(vb, vt);
        attn3<<<dim3(1792), blk, 0, stream>>>(qb, kb, vt, ab);
        gemm_bb<false, false><<<dim3(32, 28), blk, 0, stream>>>(ab, Wob, nullptr, out, 3584, 3584);
    } else {
        unsigned short* qb = (unsigned short*)d_ws;
        unsigned short* kb = qb + NQ;
        unsigned short* vb = kb + NKV;
        unsigned short* vt = vb + NKV;
        unsigned short* ab = vt + NKV;

        gemm_nt<false, true, true><<<dim3(32, 28), blk, 0, stream>>>(hs, Wq, bq, qb, 3584, 3584);
        gemm_nt<false, true, true><<<dim3(32, 4),  blk, 0, stream>>>(hs, Wk, bk, kb, 3584, 512);
        gemm_nt<false, true, true><<<dim3(32, 4),  blk, 0, stream>>>(hs, Wv, bv, vb, 3584, 512);
        rope2<<<dim3(4096), blk, 0, stream>>>(qb, kb, cosp, sinp);
        transpose_v<<<dim3(64, 8), blk, 0, stream>>>(vb, vt);
        attn3<<<dim3(1792), blk, 0, stream>>>(qb, kb, vt, ab);
        gemm_nt<true, false, false><<<dim3(32, 28), blk, 0, stream>>>(ab, Wo, nullptr, out, 3584, 3584);
    }
}

// Round 2
// 1090.684 us; speedup vs baseline: 1.1128x; 1.0629x over previous
//
#include <hip/hip_runtime.h>

// ---------------------------------------------------------------------------
// Qwen2 attention forward: QKV proj + RoPE + causal GQA attention + O proj
// B=2 S=2048 HIDDEN=3584 NH=28 NKV=4 D=128
// ---------------------------------------------------------------------------

typedef __bf16 bf16x8 __attribute__((ext_vector_type(8)));
typedef float floatx4 __attribute__((ext_vector_type(4)));
typedef unsigned short ushort8v __attribute__((ext_vector_type(8)));
typedef unsigned short ushort4v __attribute__((ext_vector_type(4)));

__device__ __forceinline__ unsigned short f2bf(float f) {
    union { float f; unsigned int u; } v; v.f = f;
    return (unsigned short)((v.u + 0x7fffu + ((v.u >> 16) & 1u)) >> 16);
}
__device__ __forceinline__ float bf2f(unsigned short b) {
    union { unsigned int u; float f; } v; v.u = ((unsigned int)b) << 16;
    return v.f;
}
__device__ __forceinline__ floatx4 mfma16(bf16x8 a, bf16x8 b, floatx4 c) {
    return __builtin_amdgcn_mfma_f32_16x16x32_bf16(a, b, c, 0, 0, 0);
}
__device__ __forceinline__ bf16x8 ld8(const unsigned short* p) {
    ushort8v t = *(const ushort8v*)p;
    return __builtin_bit_cast(bf16x8, t);
}

// async global->LDS, 16B per lane; LDS dest = wave-uniform base + lane*16
#define GLL16(g, l) __builtin_amdgcn_global_load_lds( \
    (const __attribute__((address_space(1))) void*)(g), \
    (__attribute__((address_space(3))) void*)(l), 16, 0, 0)

// ---------------------------------------------------------------------------
// fp32 -> bf16 bulk convert of 5 arrays (vec4 granularity)
// ---------------------------------------------------------------------------
__global__ __launch_bounds__(256) void convert5(
    const float* __restrict__ s0, const float* __restrict__ s1,
    const float* __restrict__ s2, const float* __restrict__ s3,
    const float* __restrict__ s4,
    unsigned short* __restrict__ d0, unsigned short* __restrict__ d1,
    unsigned short* __restrict__ d2, unsigned short* __restrict__ d3,
    unsigned short* __restrict__ d4,
    int n0, int n1, int n2, int n3, int n4)
{
    int total = n0 + n1 + n2 + n3 + n4;
    for (int i = blockIdx.x * blockDim.x + threadIdx.x; i < total;
         i += gridDim.x * blockDim.x) {
        const float* s; unsigned short* d; int j = i;
        if (j < n0)      { s = s0; d = d0; }
        else { j -= n0; if (j < n1) { s = s1; d = d1; }
        else { j -= n1; if (j < n2) { s = s2; d = d2; }
        else { j -= n2; if (j < n3) { s = s3; d = d3; }
        else { j -= n3;   s = s4; d = d4; } } } }
        float4 v = ((const float4*)s)[j];
        ushort4v o;
        o[0] = f2bf(v.x); o[1] = f2bf(v.y); o[2] = f2bf(v.z); o[3] = f2bf(v.w);
        ((ushort4v*)d)[j] = o;
    }
}

// ---------------------------------------------------------------------------
// all-bf16 NT GEMM: C[m][n] = sum_k A[m][k]*B[n][k] (+bias[n])
// 128x128 tile, BK=32, global_load_lds staging into XOR-swizzled LDS.
// ---------------------------------------------------------------------------
template<bool HAS_BIAS, bool OUT_BF16>
__global__ __launch_bounds__(256) void gemm_bb(
    const unsigned short* __restrict__ A, const unsigned short* __restrict__ B,
    const float* __restrict__ bias, void* __restrict__ C,
    int K, int ldc)
{
    __shared__ unsigned short As[128 * 32];   // row stride 32 ushorts, swizzled
    __shared__ unsigned short Bs[128 * 32];

    const int tid = threadIdx.x, lane = tid & 63, w = tid >> 6;
    const int quad = lane >> 4, l16 = lane & 15;
    const int m0 = blockIdx.x * 128, n0 = blockIdx.y * 128;
    const int wm = (w & 1) * 64, wn = (w >> 1) * 64;

    floatx4 acc[4][4] = {};

    for (int k0 = 0; k0 < K; k0 += 32) {
        __syncthreads();
        #pragma unroll
        for (int p = 0; p < 2; ++p) {
            int c = (w * 2 + p) * 64 + lane;      // chunk 0..511
            int row = c >> 2, sp = c & 3;
            int slog = sp ^ ((row ^ (row >> 2)) & 3);
            GLL16(A + (size_t)(m0 + row) * K + k0 + slog * 8,
                  (unsigned short*)As + (w * 2 + p) * 512);
            GLL16(B + (size_t)(n0 + row) * K + k0 + slog * 8,
                  (unsigned short*)Bs + (w * 2 + p) * 512);
        }
        __syncthreads();
        bf16x8 af[4], bf[4];
        #pragma unroll
        for (int i = 0; i < 4; ++i) {
            int row = wm + i * 16 + l16;
            int sp = quad ^ ((row ^ (row >> 2)) & 3);
            af[i] = ld8((unsigned short*)As + row * 32 + sp * 8);
        }
        #pragma unroll
        for (int j = 0; j < 4; ++j) {
            int row = wn + j * 16 + l16;
            int sp = quad ^ ((row ^ (row >> 2)) & 3);
            bf[j] = ld8((unsigned short*)Bs + row * 32 + sp * 8);
        }
        #pragma unroll
        for (int i = 0; i < 4; ++i)
            #pragma unroll
            for (int j = 0; j < 4; ++j)
                acc[i][j] = mfma16(af[i], bf[j], acc[i][j]);
    }

    #pragma unroll
    for (int j = 0; j < 4; ++j) {
        int col = n0 + wn + j * 16 + l16;
        float bb = HAS_BIAS ? bias[col] : 0.0f;
        #pragma unroll
        for (int i = 0; i < 4; ++i) {
            int row = m0 + wm + i * 16 + quad * 4;
            #pragma unroll
            for (int r = 0; r < 4; ++r) {
                float v = acc[i][j][r] + bb;
                if (OUT_BF16)
                    ((unsigned short*)C)[(size_t)(row + r) * ldc + col] = f2bf(v);
                else
                    ((float*)C)[(size_t)(row + r) * ldc + col] = v;
            }
        }
    }
}

// ---------------------------------------------------------------------------
// v1 fp32-staging GEMM (fallback path when workspace is small)
// ---------------------------------------------------------------------------
template<bool A_BF16, bool HAS_BIAS, bool OUT_BF16>
__global__ __launch_bounds__(256) void gemm_nt(
    const void* __restrict__ Ap, const float* __restrict__ Bp,
    const float* __restrict__ bias, void* __restrict__ Cp,
    int K, int ldc)
{
    __shared__ unsigned short As[128][40];
    __shared__ unsigned short Bs[128][40];

    const int tid = threadIdx.x, lane = tid & 63, w = tid >> 6;
    const int quad = lane >> 4, l16 = lane & 15;
    const int m0 = blockIdx.x * 128, n0 = blockIdx.y * 128;
    const int wm = (w & 1) * 64, wn = (w >> 1) * 64;

    floatx4 acc[4][4] = {};

    for (int k0 = 0; k0 < K; k0 += 32) {
        __syncthreads();
        if (A_BF16) {
            const unsigned short* Ab = (const unsigned short*)Ap;
            #pragma unroll
            for (int p = 0; p < 2; ++p) {
                int idx = tid + p * 256;
                int row = idx >> 2, seg = idx & 3;
                ushort8v v = *(const ushort8v*)(Ab + (size_t)(m0 + row) * K + k0 + seg * 8);
                *(ushort8v*)&As[row][seg * 8] = v;
            }
        } else {
            const float* Af = (const float*)Ap;
            #pragma unroll
            for (int p = 0; p < 4; ++p) {
                int idx = tid + p * 256;
                int row = idx >> 3, seg = idx & 7;
                const float4 v = *(const float4*)(Af + (size_t)(m0 + row) * K + k0 + seg * 4);
                ushort4v b;
                b[0] = f2bf(v.x); b[1] = f2bf(v.y); b[2] = f2bf(v.z); b[3] = f2bf(v.w);
                *(ushort4v*)&As[row][seg * 4] = b;
            }
        }
        #pragma unroll
        for (int p = 0; p < 4; ++p) {
            int idx = tid + p * 256;
            int row = idx >> 3, seg = idx & 7;
            const float4 v = *(const float4*)(Bp + (size_t)(n0 + row) * K + k0 + seg * 4);
            ushort4v b;
            b[0] = f2bf(v.x); b[1] = f2bf(v.y); b[2] = f2bf(v.z); b[3] = f2bf(v.w);
            *(ushort4v*)&Bs[row][seg * 4] = b;
        }
        __syncthreads();
        bf16x8 af[4], bv[4];
        #pragma unroll
        for (int i = 0; i < 4; ++i) af[i] = ld8(&As[wm + i * 16 + l16][quad * 8]);
        #pragma unroll
        for (int j = 0; j < 4; ++j) bv[j] = ld8(&Bs[wn + j * 16 + l16][quad * 8]);
        #pragma unroll
        for (int i = 0; i < 4; ++i)
            #pragma unroll
            for (int j = 0; j < 4; ++j)
                acc[i][j] = mfma16(af[i], bv[j], acc[i][j]);
    }

    #pragma unroll
    for (int j = 0; j < 4; ++j) {
        int col = n0 + wn + j * 16 + l16;
        float bb = HAS_BIAS ? bias[col] : 0.0f;
        #pragma unroll
        for (int i = 0; i < 4; ++i) {
            int row = m0 + wm + i * 16 + quad * 4;
            #pragma unroll
            for (int r = 0; r < 4; ++r) {
                float v = acc[i][j][r] + bb;
                if (OUT_BF16)
                    ((unsigned short*)Cp)[(size_t)(row + r) * ldc + col] = f2bf(v);
                else
                    ((float*)Cp)[(size_t)(row + r) * ldc + col] = v;
            }
        }
    }
}

// ---------------------------------------------------------------------------
// RoPE in place: one block per token, 32 head-slices (28 q + 4 k)
// ---------------------------------------------------------------------------
__global__ __launch_bounds__(256) void rope2(
    unsigned short* __restrict__ Q, unsigned short* __restrict__ K,
    const float* __restrict__ cosp, const float* __restrict__ sinp)
{
    const int tok = blockIdx.x, tid = threadIdx.x;
    __shared__ float cs[128], ss[128];
    if (tid < 128) {
        cs[tid] = cosp[(size_t)tok * 128 + tid];
        ss[tid] = sinp[(size_t)tok * 128 + tid];
    }
    __syncthreads();

    ushort8v x[2], x2[2];
    unsigned short* bases[2];
    int segs[2];
    #pragma unroll
    for (int p = 0; p < 2; ++p) {
        int chunk = tid + p * 256;              // 0..511
        int hh = chunk >> 4, seg = chunk & 15;
        unsigned short* base = (hh < 28)
            ? Q + (size_t)tok * 3584 + hh * 128
            : K + (size_t)tok * 512 + (hh - 28) * 128;
        bases[p] = base; segs[p] = seg;
        x[p]  = *(const ushort8v*)(base + seg * 8);
        x2[p] = *(const ushort8v*)(base + (seg ^ 8) * 8);
    }
    __syncthreads();   // all reads complete before any thread writes
    #pragma unroll
    for (int p = 0; p < 2; ++p) {
        int seg = segs[p];
        ushort8v y;
        #pragma unroll
        for (int j = 0; j < 8; ++j) {
            int d = seg * 8 + j;
            float xv = bf2f(x[p][j]);
            float rv = bf2f(x2[p][j]);
            float rot = (seg < 8) ? -rv : rv;
            y[j] = f2bf(xv * cs[d] + rot * ss[d]);
        }
        *(ushort8v*)(bases[p] + seg * 8) = y;
    }
}

// ---------------------------------------------------------------------------
// V transpose: vb[4096 tok][512 gd] -> vt[512 gd][4096 tok]
// ---------------------------------------------------------------------------
__global__ __launch_bounds__(256) void transpose_v(
    const unsigned short* __restrict__ vb, unsigned short* __restrict__ vt)
{
    __shared__ unsigned short Ts[64][68];
    const int t0 = blockIdx.x * 64, c0 = blockIdx.y * 64;
    const int tid = threadIdx.x;
    #pragma unroll
    for (int it = 0; it < 4; ++it) {
        int idx = tid + it * 256;
        int row = idx >> 4, seg = idx & 15;
        *(ushort4v*)&Ts[row][seg * 4] =
            *(const ushort4v*)(vb + (size_t)(t0 + row) * 512 + c0 + seg * 4);
    }
    __syncthreads();
    #pragma unroll
    for (int it = 0; it < 4; ++it) {
        int idx = tid + it * 256;
        int gd = idx >> 4, seg = idx & 15;
        ushort4v y;
        #pragma unroll
        for (int j = 0; j < 4; ++j) y[j] = Ts[seg * 4 + j][gd];
        *(ushort4v*)(vt + (size_t)(c0 + gd) * 4096 + t0 + seg * 4) = y;
    }
}

// ---------------------------------------------------------------------------
// Flash attention v4: K staged async into XOR-swizzled LDS (double-buffered,
// counted vmcnt, ONE raw barrier per iter, never vmcnt(0) in the loop).
// V^T frags hoisted into regs at loop top (latency hidden under QK+softmax).
// Defer-max softmax: speculative exp with old running max; rescale path
// (shfl tree + o-rescale) only when the per-wave ballot says max grew.
// Row-sum accumulated as per-lane partials, reduced once in the epilogue.
// Grid: 1D 1792, XCD slice-pinned (bid&7 -> one (b,kvh) KV slice per L2),
// LPT (qt descending) inside each slice.
// ---------------------------------------------------------------------------
__global__ __launch_bounds__(256, 3) void attn4(
    const unsigned short* __restrict__ Q, const unsigned short* __restrict__ Kb,
    const unsigned short* __restrict__ Vt, unsigned short* __restrict__ O)
{
    const int bid   = blockIdx.x;
    const int slice = bid & 7;          // -> XCD via round-robin dispatch
    const int b     = slice & 1;
    const int kvh   = slice >> 1;
    const int j     = bid >> 3;         // 0..223 within slice
    const int qt    = 31 - (j / 7);     // LPT: heaviest q-tiles first
    const int h     = kvh * 7 + (j % 7);

    const int tid = threadIdx.x, lane = tid & 63, w = tid >> 6;
    const int quad = lane >> 4, l16 = lane & 15;

    __shared__ unsigned short Ks[2][64 * 128];   // 2 x 16KB, XOR-swizzled
    __shared__ unsigned short Ps[64][72];        // per-wave-private rows

    // Q fragments in registers (A-layout), held for whole kernel (4 loads)
    bf16x8 aq[4];
    {
        const unsigned short* qp =
            Q + (size_t)(b * 2048 + qt * 64 + w * 16 + l16) * 3584 + h * 128 + quad * 8;
        #pragma unroll
        for (int ks = 0; ks < 4; ++ks) aq[ks] = ld8(qp + ks * 32);
    }

    const unsigned short* vbase = Vt + (size_t)kvh * 128 * 4096 + b * 2048;
    const unsigned short* kbase = Kb + (size_t)(b * 2048) * 512 + kvh * 128;

    // stage one 64x128 K tile: 16 GLL16 (4/wave), linear LDS dest,
    // pre-swizzled global source: LDS[row][c16] = G[row][c16 ^ (row&7)]
    auto stageK = [&](int kt, int buf) {
        const unsigned short* kt_base = kbase + (size_t)kt * 64 * 512;
        #pragma unroll
        for (int p = 0; p < 4; ++p) {
            int u = (w * 4 + p) * 64 + lane;     // 16B-unit index 0..1023
            int row = u >> 4, c16 = u & 15;
            GLL16(kt_base + (size_t)row * 512 + ((c16 ^ (row & 7)) * 8),
                  &Ks[buf][0] + (w * 4 + p) * 512);
        }
        asm volatile("" ::: "memory");           // keep stage ops oldest
    };

    stageK(0, 0);

    floatx4 o[8] = {};
    float mrow[4], trow[4], lrow[4];
    const float cexp = 0.08838834764831845f * 1.4426950408889634f;
    const float thr_raw = 8.0f / cexp;
    #pragma unroll
    for (int r = 0; r < 4; ++r) {
        mrow[r] = -1e30f; trow[r] = -1e30f * cexp; lrow[r] = 0.f;
    }

    int cur = 0;
    for (int kt = 0; kt <= qt; ++kt) {
        // ---- V frags for this tile -> regs (in flight across the barrier) --
        bf16x8 vf[2][8];
        {
            const unsigned short* vp0 = vbase + kt * 64 + quad * 8;
            #pragma unroll
            for (int ks2 = 0; ks2 < 2; ++ks2)
                #pragma unroll
                for (int d4 = 0; d4 < 8; ++d4)
                    vf[ks2][d4] = ld8(vp0 + ks2 * 32 + (size_t)(d4 * 16 + l16) * 4096);
        }
        // drain this tile's K stage (oldest vmem ops); V loads stay in flight
        asm volatile("s_waitcnt vmcnt(16)\n\ts_barrier" ::: "memory");
        if (kt < qt) stageK(kt + 1, cur ^ 1);

        // ---- S = Q K^T from swizzled LDS ----
        floatx4 s[4] = {};
        #pragma unroll
        for (int ks = 0; ks < 4; ++ks) {
            bf16x8 kf[4];
            #pragma unroll
            for (int n4 = 0; n4 < 4; ++n4) {
                int row = n4 * 16 + l16;
                kf[n4] = ld8(&Ks[cur][row * 128 + (((ks * 4 + quad) ^ (row & 7)) * 8)]);
            }
            #pragma unroll
            for (int n4 = 0; n4 < 4; ++n4)
                s[n4] = mfma16(aq[ks], kf[n4], s[n4]);
        }

        // ---- defer-max softmax: speculative exp with old running max ----
        const bool diag = (kt == qt);
        float pv[4][4];
        int need = 0;
        #pragma unroll
        for (int r = 0; r < 4; ++r) {
            if (diag) {
                int qg = qt * 64 + w * 16 + quad * 4 + r;
                int kg = kt * 64 + l16;
                if (kg      > qg) s[0][r] = -1e30f;
                if (kg + 16 > qg) s[1][r] = -1e30f;
                if (kg + 32 > qg) s[2][r] = -1e30f;
                if (kg + 48 > qg) s[3][r] = -1e30f;
            }
            float mx = fmaxf(fmaxf(s[0][r], s[1][r]), fmaxf(s[2][r], s[3][r]));
            need |= (mx > mrow[r] + thr_raw) ? 1 : 0;
            pv[r][0] = __builtin_amdgcn_exp2f(fmaf(s[0][r], cexp, -trow[r]));
            pv[r][1] = __builtin_amdgcn_exp2f(fmaf(s[1][r], cexp, -trow[r]));
            pv[r][2] = __builtin_amdgcn_exp2f(fmaf(s[2][r], cexp, -trow[r]));
            pv[r][3] = __builtin_amdgcn_exp2f(fmaf(s[3][r], cexp, -trow[r]));
        }
        if (__any(need)) {                       // rare after kt==0
            #pragma unroll
            for (int r = 0; r < 4; ++r) {
                float mx = fmaxf(fmaxf(s[0][r], s[1][r]), fmaxf(s[2][r], s[3][r]));
                #pragma unroll
                for (int off = 1; off < 16; off <<= 1)
                    mx = fmaxf(mx, __shfl_xor(mx, off, 64));
                float mnew  = fmaxf(mrow[r], mx);
                float alpha = __builtin_amdgcn_exp2f((mrow[r] - mnew) * cexp);
                mrow[r] = mnew; trow[r] = mnew * cexp;
                lrow[r] *= alpha;
                #pragma unroll
                for (int d4 = 0; d4 < 8; ++d4) o[d4][r] *= alpha;
                pv[r][0] = __builtin_amdgcn_exp2f(fmaf(s[0][r], cexp, -trow[r]));
                pv[r][1] = __builtin_amdgcn_exp2f(fmaf(s[1][r], cexp, -trow[r]));
                pv[r][2] = __builtin_amdgcn_exp2f(fmaf(s[2][r], cexp, -trow[r]));
                pv[r][3] = __builtin_amdgcn_exp2f(fmaf(s[3][r], cexp, -trow[r]));
            }
        }
        #pragma unroll
        for (int r = 0; r < 4; ++r) {
            lrow[r] += pv[r][0] + pv[r][1] + pv[r][2] + pv[r][3];
            int prow = w * 16 + quad * 4 + r;
            Ps[prow][ 0 + l16] = f2bf(pv[r][0]);
            Ps[prow][16 + l16] = f2bf(pv[r][1]);
            Ps[prow][32 + l16] = f2bf(pv[r][2]);
            Ps[prow][48 + l16] = f2bf(pv[r][3]);
        }

        // ---- O += P V (V already in regs) ----
        #pragma unroll
        for (int ks2 = 0; ks2 < 2; ++ks2) {
            bf16x8 ap = ld8(&Ps[w * 16 + l16][ks2 * 32 + quad * 8]);
            #pragma unroll
            for (int d4 = 0; d4 < 8; ++d4)
                o[d4] = mfma16(ap, vf[ks2][d4], o[d4]);
        }
        cur ^= 1;
    }

    // reduce per-lane partial row sums across the 16 lanes of each row (once)
    #pragma unroll
    for (int r = 0; r < 4; ++r) {
        float l = lrow[r];
        #pragma unroll
        for (int off = 1; off < 16; off <<= 1)
            l += __shfl_xor(l, off, 64);
        lrow[r] = 1.0f / l;
    }
    #pragma unroll
    for (int d4 = 0; d4 < 8; ++d4) {
        int col = h * 128 + d4 * 16 + l16;
        #pragma unroll
        for (int r = 0; r < 4; ++r) {
            int row = b * 2048 + qt * 64 + w * 16 + quad * 4 + r;
            O[(size_t)row * 3584 + col] = f2bf(o[d4][r] * lrow[r]);
        }
    }
}

// ---------------------------------------------------------------------------
extern "C" void kernel_launch(void* const* d_in, const int* in_sizes, int n_in,
                              void* d_out, int out_size, void* d_ws, size_t ws_size,
                              hipStream_t stream)
{
    (void)in_sizes; (void)n_in; (void)out_size;
    const float* hs   = (const float*)d_in[0];
    const float* cosp = (const float*)d_in[1];
    const float* sinp = (const float*)d_in[2];
    const float* Wq   = (const float*)d_in[3];
    const float* bq   = (const float*)d_in[4];
    const float* Wk   = (const float*)d_in[5];
    const float* bk   = (const float*)d_in[6];
    const float* Wv   = (const float*)d_in[7];
    const float* bv   = (const float*)d_in[8];
    const float* Wo   = (const float*)d_in[9];
    float* out = (float*)d_out;

    const size_t NHS = 14680064;   // 4096*3584
    const size_t NWQ = 12845056;   // 3584*3584
    const size_t NWKV = 1835008;   // 512*3584
    const size_t NWO = 12845056;
    const size_t NQ  = 14680064;
    const size_t NKV = 2097152;    // 4096*512

    const size_t need = 2 * (NHS + NQ + NQ + 3 * NKV + NWQ + 2 * NWKV + NWO);
    dim3 blk(256);

    if (ws_size >= need) {
        unsigned short* hb  = (unsigned short*)d_ws;
        unsigned short* qb  = hb + NHS;
        unsigned short* ab  = qb + NQ;
        unsigned short* kb  = ab + NQ;
        unsigned short* vb  = kb + NKV;
        unsigned short* vt  = vb + NKV;
        unsigned short* Wqb = vt + NKV;
        unsigned short* Wkb = Wqb + NWQ;
        unsigned short* Wvb = Wkb + NWKV;
        unsigned short* Wob = Wvb + NWKV;

        convert5<<<dim3(1024), blk, 0, stream>>>(
            hs, Wq, Wk, Wv, Wo, hb, Wqb, Wkb, Wvb, Wob,
            (int)(NHS / 4), (int)(NWQ / 4), (int)(NWKV / 4), (int)(NWKV / 4), (int)(NWO / 4));

        gemm_bb<true, true><<<dim3(32, 28), blk, 0, stream>>>(hb, Wqb, bq, qb, 3584, 3584);
        gemm_bb<true, true><<<dim3(32, 4),  blk, 0, stream>>>(hb, Wkb, bk, kb, 3584, 512);
        gemm_bb<true, true><<<dim3(32, 4),  blk, 0, stream>>>(hb, Wvb, bv, vb, 3584, 512);
        rope2<<<dim3(4096), blk, 0, stream>>>(qb, kb, cosp, sinp);
        transpose_v<<<dim3(64, 8), blk, 0, stream>>>(vb, vt);
        attn4<<<dim3(1792), blk, 0, stream>>>(qb, kb, vt, ab);
        gemm_bb<false, false><<<dim3(32, 28), blk, 0, stream>>>(ab, Wob, nullptr, out, 3584, 3584);
    } else {
        unsigned short* qb = (unsigned short*)d_ws;
        unsigned short* kb = qb + NQ;
        unsigned short* vb = kb + NKV;
        unsigned short* vt = vb + NKV;
        unsigned short* ab = vt + NKV;

        gemm_nt<false, true, true><<<dim3(32, 28), blk, 0, stream>>>(hs, Wq, bq, qb, 3584, 3584);
        gemm_nt<false, true, true><<<dim3(32, 4),  blk, 0, stream>>>(hs, Wk, bk, kb, 3584, 512);
        gemm_nt<false, true, true><<<dim3(32, 4),  blk, 0, stream>>>(hs, Wv, bv, vb, 3584, 512);
        rope2<<<dim3(4096), blk, 0, stream>>>(qb, kb, cosp, sinp);
        transpose_v<<<dim3(64, 8), blk, 0, stream>>>(vb, vt);
        attn4<<<dim3(1792), blk, 0, stream>>>(qb, kb, vt, ab);
        gemm_nt<true, false, false><<<dim3(32, 28), blk, 0, stream>>>(ab, Wo, nullptr, out, 3584, 3584);
    }
}

// Round 3
// 839.023 us; speedup vs baseline: 1.4466x; 1.2999x over previous
//
#include <hip/hip_runtime.h>

// ---------------------------------------------------------------------------
// Qwen2 attention forward: QKV proj + RoPE + causal GQA attention + O proj
// B=2 S=2048 HIDDEN=3584 NH=28 NKV=4 D=128
// ---------------------------------------------------------------------------

typedef __bf16 bf16x8 __attribute__((ext_vector_type(8)));
typedef float floatx4 __attribute__((ext_vector_type(4)));
typedef unsigned short ushort8v __attribute__((ext_vector_type(8)));
typedef unsigned short ushort4v __attribute__((ext_vector_type(4)));

__device__ __forceinline__ unsigned short f2bf(float f) {
    union { float f; unsigned int u; } v; v.f = f;
    return (unsigned short)((v.u + 0x7fffu + ((v.u >> 16) & 1u)) >> 16);
}
__device__ __forceinline__ float bf2f(unsigned short b) {
    union { unsigned int u; float f; } v; v.u = ((unsigned int)b) << 16;
    return v.f;
}
__device__ __forceinline__ floatx4 mfma16(bf16x8 a, bf16x8 b, floatx4 c) {
    return __builtin_amdgcn_mfma_f32_16x16x32_bf16(a, b, c, 0, 0, 0);
}
__device__ __forceinline__ bf16x8 ld8(const unsigned short* p) {
    ushort8v t = *(const ushort8v*)p;
    return __builtin_bit_cast(bf16x8, t);
}

// async global->LDS, 16B per lane; LDS dest = wave-uniform base + lane*16
#define GLL16(g, l) __builtin_amdgcn_global_load_lds( \
    (const __attribute__((address_space(1))) void*)(g), \
    (__attribute__((address_space(3))) void*)(l), 16, 0, 0)

// ---------------------------------------------------------------------------
// fp32 -> bf16 bulk convert of 5 arrays (vec4 granularity)
// ---------------------------------------------------------------------------
__global__ __launch_bounds__(256) void convert5(
    const float* __restrict__ s0, const float* __restrict__ s1,
    const float* __restrict__ s2, const float* __restrict__ s3,
    const float* __restrict__ s4,
    unsigned short* __restrict__ d0, unsigned short* __restrict__ d1,
    unsigned short* __restrict__ d2, unsigned short* __restrict__ d3,
    unsigned short* __restrict__ d4,
    int n0, int n1, int n2, int n3, int n4)
{
    int total = n0 + n1 + n2 + n3 + n4;
    for (int i = blockIdx.x * blockDim.x + threadIdx.x; i < total;
         i += gridDim.x * blockDim.x) {
        const float* s; unsigned short* d; int j = i;
        if (j < n0)      { s = s0; d = d0; }
        else { j -= n0; if (j < n1) { s = s1; d = d1; }
        else { j -= n1; if (j < n2) { s = s2; d = d2; }
        else { j -= n2; if (j < n3) { s = s3; d = d3; }
        else { j -= n3;   s = s4; d = d4; } } } }
        float4 v = ((const float4*)s)[j];
        ushort4v o;
        o[0] = f2bf(v.x); o[1] = f2bf(v.y); o[2] = f2bf(v.z); o[3] = f2bf(v.w);
        ((ushort4v*)d)[j] = o;
    }
}

// ---------------------------------------------------------------------------
// all-bf16 NT GEMM: C[m][n] = sum_k A[m][k]*B[n][k] (+bias[n])
// 128x128 tile, BK=32, global_load_lds staging into XOR-swizzled LDS.
// ---------------------------------------------------------------------------
template<bool HAS_BIAS, bool OUT_BF16>
__global__ __launch_bounds__(256) void gemm_bb(
    const unsigned short* __restrict__ A, const unsigned short* __restrict__ B,
    const float* __restrict__ bias, void* __restrict__ C,
    int K, int ldc)
{
    __shared__ unsigned short As[128 * 32];   // row stride 32 ushorts, swizzled
    __shared__ unsigned short Bs[128 * 32];

    const int tid = threadIdx.x, lane = tid & 63, w = tid >> 6;
    const int quad = lane >> 4, l16 = lane & 15;
    const int m0 = blockIdx.x * 128, n0 = blockIdx.y * 128;
    const int wm = (w & 1) * 64, wn = (w >> 1) * 64;

    floatx4 acc[4][4] = {};

    for (int k0 = 0; k0 < K; k0 += 32) {
        __syncthreads();
        #pragma unroll
        for (int p = 0; p < 2; ++p) {
            int c = (w * 2 + p) * 64 + lane;      // chunk 0..511
            int row = c >> 2, sp = c & 3;
            int slog = sp ^ ((row ^ (row >> 2)) & 3);
            GLL16(A + (size_t)(m0 + row) * K + k0 + slog * 8,
                  (unsigned short*)As + (w * 2 + p) * 512);
            GLL16(B + (size_t)(n0 + row) * K + k0 + slog * 8,
                  (unsigned short*)Bs + (w * 2 + p) * 512);
        }
        __syncthreads();
        bf16x8 af[4], bf[4];
        #pragma unroll
        for (int i = 0; i < 4; ++i) {
            int row = wm + i * 16 + l16;
            int sp = quad ^ ((row ^ (row >> 2)) & 3);
            af[i] = ld8((unsigned short*)As + row * 32 + sp * 8);
        }
        #pragma unroll
        for (int j = 0; j < 4; ++j) {
            int row = wn + j * 16 + l16;
            int sp = quad ^ ((row ^ (row >> 2)) & 3);
            bf[j] = ld8((unsigned short*)Bs + row * 32 + sp * 8);
        }
        #pragma unroll
        for (int i = 0; i < 4; ++i)
            #pragma unroll
            for (int j = 0; j < 4; ++j)
                acc[i][j] = mfma16(af[i], bf[j], acc[i][j]);
    }

    #pragma unroll
    for (int j = 0; j < 4; ++j) {
        int col = n0 + wn + j * 16 + l16;
        float bb = HAS_BIAS ? bias[col] : 0.0f;
        #pragma unroll
        for (int i = 0; i < 4; ++i) {
            int row = m0 + wm + i * 16 + quad * 4;
            #pragma unroll
            for (int r = 0; r < 4; ++r) {
                float v = acc[i][j][r] + bb;
                if (OUT_BF16)
                    ((unsigned short*)C)[(size_t)(row + r) * ldc + col] = f2bf(v);
                else
                    ((float*)C)[(size_t)(row + r) * ldc + col] = v;
            }
        }
    }
}

// ---------------------------------------------------------------------------
// v1 fp32-staging GEMM (fallback path when workspace is small)
// ---------------------------------------------------------------------------
template<bool A_BF16, bool HAS_BIAS, bool OUT_BF16>
__global__ __launch_bounds__(256) void gemm_nt(
    const void* __restrict__ Ap, const float* __restrict__ Bp,
    const float* __restrict__ bias, void* __restrict__ Cp,
    int K, int ldc)
{
    __shared__ unsigned short As[128][40];
    __shared__ unsigned short Bs[128][40];

    const int tid = threadIdx.x, lane = tid & 63, w = tid >> 6;
    const int quad = lane >> 4, l16 = lane & 15;
    const int m0 = blockIdx.x * 128, n0 = blockIdx.y * 128;
    const int wm = (w & 1) * 64, wn = (w >> 1) * 64;

    floatx4 acc[4][4] = {};

    for (int k0 = 0; k0 < K; k0 += 32) {
        __syncthreads();
        if (A_BF16) {
            const unsigned short* Ab = (const unsigned short*)Ap;
            #pragma unroll
            for (int p = 0; p < 2; ++p) {
                int idx = tid + p * 256;
                int row = idx >> 2, seg = idx & 3;
                ushort8v v = *(const ushort8v*)(Ab + (size_t)(m0 + row) * K + k0 + seg * 8);
                *(ushort8v*)&As[row][seg * 8] = v;
            }
        } else {
            const float* Af = (const float*)Ap;
            #pragma unroll
            for (int p = 0; p < 4; ++p) {
                int idx = tid + p * 256;
                int row = idx >> 3, seg = idx & 7;
                const float4 v = *(const float4*)(Af + (size_t)(m0 + row) * K + k0 + seg * 4);
                ushort4v b;
                b[0] = f2bf(v.x); b[1] = f2bf(v.y); b[2] = f2bf(v.z); b[3] = f2bf(v.w);
                *(ushort4v*)&As[row][seg * 4] = b;
            }
        }
        #pragma unroll
        for (int p = 0; p < 4; ++p) {
            int idx = tid + p * 256;
            int row = idx >> 3, seg = idx & 7;
            const float4 v = *(const float4*)(Bp + (size_t)(n0 + row) * K + k0 + seg * 4);
            ushort4v b;
            b[0] = f2bf(v.x); b[1] = f2bf(v.y); b[2] = f2bf(v.z); b[3] = f2bf(v.w);
            *(ushort4v*)&Bs[row][seg * 4] = b;
        }
        __syncthreads();
        bf16x8 af[4], bv[4];
        #pragma unroll
        for (int i = 0; i < 4; ++i) af[i] = ld8(&As[wm + i * 16 + l16][quad * 8]);
        #pragma unroll
        for (int j = 0; j < 4; ++j) bv[j] = ld8(&Bs[wn + j * 16 + l16][quad * 8]);
        #pragma unroll
        for (int i = 0; i < 4; ++i)
            #pragma unroll
            for (int j = 0; j < 4; ++j)
                acc[i][j] = mfma16(af[i], bv[j], acc[i][j]);
    }

    #pragma unroll
    for (int j = 0; j < 4; ++j) {
        int col = n0 + wn + j * 16 + l16;
        float bb = HAS_BIAS ? bias[col] : 0.0f;
        #pragma unroll
        for (int i = 0; i < 4; ++i) {
            int row = m0 + wm + i * 16 + quad * 4;
            #pragma unroll
            for (int r = 0; r < 4; ++r) {
                float v = acc[i][j][r] + bb;
                if (OUT_BF16)
                    ((unsigned short*)Cp)[(size_t)(row + r) * ldc + col] = f2bf(v);
                else
                    ((float*)Cp)[(size_t)(row + r) * ldc + col] = v;
            }
        }
    }
}

// ---------------------------------------------------------------------------
// RoPE in place: one block per token, 32 head-slices (28 q + 4 k)
// ---------------------------------------------------------------------------
__global__ __launch_bounds__(256) void rope2(
    unsigned short* __restrict__ Q, unsigned short* __restrict__ K,
    const float* __restrict__ cosp, const float* __restrict__ sinp)
{
    const int tok = blockIdx.x, tid = threadIdx.x;
    __shared__ float cs[128], ss[128];
    if (tid < 128) {
        cs[tid] = cosp[(size_t)tok * 128 + tid];
        ss[tid] = sinp[(size_t)tok * 128 + tid];
    }
    __syncthreads();

    ushort8v x[2], x2[2];
    unsigned short* bases[2];
    int segs[2];
    #pragma unroll
    for (int p = 0; p < 2; ++p) {
        int chunk = tid + p * 256;              // 0..511
        int hh = chunk >> 4, seg = chunk & 15;
        unsigned short* base = (hh < 28)
            ? Q + (size_t)tok * 3584 + hh * 128
            : K + (size_t)tok * 512 + (hh - 28) * 128;
        bases[p] = base; segs[p] = seg;
        x[p]  = *(const ushort8v*)(base + seg * 8);
        x2[p] = *(const ushort8v*)(base + (seg ^ 8) * 8);
    }
    __syncthreads();   // all reads complete before any thread writes
    #pragma unroll
    for (int p = 0; p < 2; ++p) {
        int seg = segs[p];
        ushort8v y;
        #pragma unroll
        for (int j = 0; j < 8; ++j) {
            int d = seg * 8 + j;
            float xv = bf2f(x[p][j]);
            float rv = bf2f(x2[p][j]);
            float rot = (seg < 8) ? -rv : rv;
            y[j] = f2bf(xv * cs[d] + rot * ss[d]);
        }
        *(ushort8v*)(bases[p] + seg * 8) = y;
    }
}

// ---------------------------------------------------------------------------
// V transpose: vb[4096 tok][512 gd] -> vt[512 gd][4096 tok]
// ---------------------------------------------------------------------------
__global__ __launch_bounds__(256) void transpose_v(
    const unsigned short* __restrict__ vb, unsigned short* __restrict__ vt)
{
    __shared__ unsigned short Ts[64][68];
    const int t0 = blockIdx.x * 64, c0 = blockIdx.y * 64;
    const int tid = threadIdx.x;
    #pragma unroll
    for (int it = 0; it < 4; ++it) {
        int idx = tid + it * 256;
        int row = idx >> 4, seg = idx & 15;
        *(ushort4v*)&Ts[row][seg * 4] =
            *(const ushort4v*)(vb + (size_t)(t0 + row) * 512 + c0 + seg * 4);
    }
    __syncthreads();
    #pragma unroll
    for (int it = 0; it < 4; ++it) {
        int idx = tid + it * 256;
        int gd = idx >> 4, seg = idx & 15;
        ushort4v y;
        #pragma unroll
        for (int j = 0; j < 4; ++j) y[j] = Ts[seg * 4 + j][gd];
        *(ushort4v*)(vt + (size_t)(c0 + gd) * 4096 + t0 + seg * 4) = y;
    }
}

// ---------------------------------------------------------------------------
// Flash attention v5: K AND V both staged async into XOR-swizzled LDS,
// double-buffered, ONE vmcnt(0)+barrier per iter (stage ops for tile kt were
// issued a full iteration earlier -> drain is free). No V regs held across
// softmax (fixes v4's scratch spills: 133MB WRITE_SIZE -> ~29MB).
// Defer-max softmax (rescale path only when ballot fires); per-lane row-sum
// partials reduced once in epilogue. s_setprio around MFMA clusters (T5).
// Grid: 1D 1792, XCD slice-pinned (bid&7), LPT (qt desc) inside each slice.
// ---------------------------------------------------------------------------
__global__ __launch_bounds__(256, 2) void attn5(
    const unsigned short* __restrict__ Q, const unsigned short* __restrict__ Kb,
    const unsigned short* __restrict__ Vt, unsigned short* __restrict__ O)
{
    const int bid   = blockIdx.x;
    const int slice = bid & 7;          // -> XCD via round-robin dispatch
    const int b     = slice & 1;
    const int kvh   = slice >> 1;
    const int j     = bid >> 3;         // 0..223 within slice
    const int qt    = 31 - (j / 7);     // LPT: heaviest q-tiles first
    const int h     = kvh * 7 + (j % 7);

    const int tid = threadIdx.x, lane = tid & 63, w = tid >> 6;
    const int quad = lane >> 4, l16 = lane & 15;

    __shared__ unsigned short Ks[2][64 * 128];   // [key][d], XOR-swizzled
    __shared__ unsigned short Vs[2][128 * 64];   // [d][key], XOR-swizzled
    __shared__ unsigned short Ps[64][72];        // per-wave-private rows

    // Q fragments in registers (A-layout), held for whole kernel (4 loads)
    bf16x8 aq[4];
    {
        const unsigned short* qp =
            Q + (size_t)(b * 2048 + qt * 64 + w * 16 + l16) * 3584 + h * 128 + quad * 8;
        #pragma unroll
        for (int ks = 0; ks < 4; ++ks) aq[ks] = ld8(qp + ks * 32);
    }

    const unsigned short* vbase = Vt + (size_t)kvh * 128 * 4096 + b * 2048;
    const unsigned short* kbase = Kb + (size_t)(b * 2048) * 512 + kvh * 128;

    // stage one 64x128 K tile: 16 GLL16 (4/wave), linear LDS dest,
    // pre-swizzled global source: LDS[row][c16] = G[row][c16 ^ (row&7)]
    auto stageK = [&](int kt, int buf) {
        const unsigned short* kt_base = kbase + (size_t)kt * 64 * 512;
        #pragma unroll
        for (int p = 0; p < 4; ++p) {
            int u = (w * 4 + p) * 64 + lane;     // 16B-unit index 0..1023
            int row = u >> 4, c16 = u & 15;
            GLL16(kt_base + (size_t)row * 512 + ((c16 ^ (row & 7)) * 8),
                  &Ks[buf][0] + (w * 4 + p) * 512);
        }
        asm volatile("" ::: "memory");
    };
    // stage one 128x64 V^T tile: 16 GLL16 (4/wave), rows d (128B each,
    // 8 units), pre-swizzled source: LDS[d][c16] = G[d][c16 ^ (d&7)]
    auto stageV = [&](int kt, int buf) {
        const unsigned short* vt_base = vbase + kt * 64;
        #pragma unroll
        for (int p = 0; p < 4; ++p) {
            int u = (w * 4 + p) * 64 + lane;     // 16B-unit index 0..1023
            int d = u >> 3, c16 = u & 7;
            GLL16(vt_base + (size_t)d * 4096 + ((c16 ^ (d & 7)) * 8),
                  &Vs[buf][0] + (w * 4 + p) * 512);
        }
        asm volatile("" ::: "memory");
    };

    stageK(0, 0);
    stageV(0, 0);

    floatx4 o[8] = {};
    float mrow[4], trow[4], lrow[4];
    const float cexp = 0.08838834764831845f * 1.4426950408889634f;
    const float thr_raw = 8.0f / cexp;
    #pragma unroll
    for (int r = 0; r < 4; ++r) {
        mrow[r] = -1e30f; trow[r] = -1e30f * cexp; lrow[r] = 0.f;
    }

    int cur = 0;
    for (int kt = 0; kt <= qt; ++kt) {
        // tile kt's 32 stage ops were issued one full iteration ago
        asm volatile("s_waitcnt vmcnt(0)\n\ts_barrier" ::: "memory");
        if (kt < qt) { stageK(kt + 1, cur ^ 1); stageV(kt + 1, cur ^ 1); }

        // ---- S = Q K^T from swizzled LDS ----
        floatx4 s[4] = {};
        __builtin_amdgcn_s_setprio(1);
        #pragma unroll
        for (int ks = 0; ks < 4; ++ks) {
            bf16x8 kf[4];
            #pragma unroll
            for (int n4 = 0; n4 < 4; ++n4) {
                int row = n4 * 16 + l16;
                kf[n4] = ld8(&Ks[cur][row * 128 + (((ks * 4 + quad) ^ (row & 7)) * 8)]);
            }
            #pragma unroll
            for (int n4 = 0; n4 < 4; ++n4)
                s[n4] = mfma16(aq[ks], kf[n4], s[n4]);
        }
        __builtin_amdgcn_s_setprio(0);

        // ---- defer-max softmax: speculative exp with old running max ----
        const bool diag = (kt == qt);
        float pv[4][4];
        int need = 0;
        #pragma unroll
        for (int r = 0; r < 4; ++r) {
            if (diag) {
                int qg = qt * 64 + w * 16 + quad * 4 + r;
                int kg = kt * 64 + l16;
                if (kg      > qg) s[0][r] = -1e30f;
                if (kg + 16 > qg) s[1][r] = -1e30f;
                if (kg + 32 > qg) s[2][r] = -1e30f;
                if (kg + 48 > qg) s[3][r] = -1e30f;
            }
            float mx = fmaxf(fmaxf(s[0][r], s[1][r]), fmaxf(s[2][r], s[3][r]));
            need |= (mx > mrow[r] + thr_raw) ? 1 : 0;
            pv[r][0] = __builtin_amdgcn_exp2f(fmaf(s[0][r], cexp, -trow[r]));
            pv[r][1] = __builtin_amdgcn_exp2f(fmaf(s[1][r], cexp, -trow[r]));
            pv[r][2] = __builtin_amdgcn_exp2f(fmaf(s[2][r], cexp, -trow[r]));
            pv[r][3] = __builtin_amdgcn_exp2f(fmaf(s[3][r], cexp, -trow[r]));
        }
        if (__any(need)) {                       // rare after kt==0
            #pragma unroll
            for (int r = 0; r < 4; ++r) {
                float mx = fmaxf(fmaxf(s[0][r], s[1][r]), fmaxf(s[2][r], s[3][r]));
                #pragma unroll
                for (int off = 1; off < 16; off <<= 1)
                    mx = fmaxf(mx, __shfl_xor(mx, off, 64));
                float mnew  = fmaxf(mrow[r], mx);
                float alpha = __builtin_amdgcn_exp2f((mrow[r] - mnew) * cexp);
                mrow[r] = mnew; trow[r] = mnew * cexp;
                lrow[r] *= alpha;
                #pragma unroll
                for (int d4 = 0; d4 < 8; ++d4) o[d4][r] *= alpha;
                pv[r][0] = __builtin_amdgcn_exp2f(fmaf(s[0][r], cexp, -trow[r]));
                pv[r][1] = __builtin_amdgcn_exp2f(fmaf(s[1][r], cexp, -trow[r]));
                pv[r][2] = __builtin_amdgcn_exp2f(fmaf(s[2][r], cexp, -trow[r]));
                pv[r][3] = __builtin_amdgcn_exp2f(fmaf(s[3][r], cexp, -trow[r]));
            }
        }
        #pragma unroll
        for (int r = 0; r < 4; ++r) {
            lrow[r] += pv[r][0] + pv[r][1] + pv[r][2] + pv[r][3];
            int prow = w * 16 + quad * 4 + r;
            Ps[prow][ 0 + l16] = f2bf(pv[r][0]);
            Ps[prow][16 + l16] = f2bf(pv[r][1]);
            Ps[prow][32 + l16] = f2bf(pv[r][2]);
            Ps[prow][48 + l16] = f2bf(pv[r][3]);
        }

        // ---- O += P V (V^T B-frags from swizzled LDS) ----
        __builtin_amdgcn_s_setprio(1);
        #pragma unroll
        for (int ks2 = 0; ks2 < 2; ++ks2) {
            bf16x8 ap = ld8(&Ps[w * 16 + l16][ks2 * 32 + quad * 8]);
            #pragma unroll
            for (int d4 = 0; d4 < 8; ++d4) {
                int d = d4 * 16 + l16;
                int sp = (ks2 * 4 + quad) ^ (d & 7);
                bf16x8 bv = ld8(&Vs[cur][d * 64 + sp * 8]);
                o[d4] = mfma16(ap, bv, o[d4]);
            }
        }
        __builtin_amdgcn_s_setprio(0);
        cur ^= 1;
    }

    // reduce per-lane partial row sums across the 16 lanes of each row (once)
    #pragma unroll
    for (int r = 0; r < 4; ++r) {
        float l = lrow[r];
        #pragma unroll
        for (int off = 1; off < 16; off <<= 1)
            l += __shfl_xor(l, off, 64);
        lrow[r] = 1.0f / l;
    }
    #pragma unroll
    for (int d4 = 0; d4 < 8; ++d4) {
        int col = h * 128 + d4 * 16 + l16;
        #pragma unroll
        for (int r = 0; r < 4; ++r) {
            int row = b * 2048 + qt * 64 + w * 16 + quad * 4 + r;
            O[(size_t)row * 3584 + col] = f2bf(o[d4][r] * lrow[r]);
        }
    }
}

// ---------------------------------------------------------------------------
extern "C" void kernel_launch(void* const* d_in, const int* in_sizes, int n_in,
                              void* d_out, int out_size, void* d_ws, size_t ws_size,
                              hipStream_t stream)
{
    (void)in_sizes; (void)n_in; (void)out_size;
    const float* hs   = (const float*)d_in[0];
    const float* cosp = (const float*)d_in[1];
    const float* sinp = (const float*)d_in[2];
    const float* Wq   = (const float*)d_in[3];
    const float* bq   = (const float*)d_in[4];
    const float* Wk   = (const float*)d_in[5];
    const float* bk   = (const float*)d_in[6];
    const float* Wv   = (const float*)d_in[7];
    const float* bv   = (const float*)d_in[8];
    const float* Wo   = (const float*)d_in[9];
    float* out = (float*)d_out;

    const size_t NHS = 14680064;   // 4096*3584
    const size_t NWQ = 12845056;   // 3584*3584
    const size_t NWKV = 1835008;   // 512*3584
    const size_t NWO = 12845056;
    const size_t NQ  = 14680064;
    const size_t NKV = 2097152;    // 4096*512

    const size_t need = 2 * (NHS + NQ + NQ + 3 * NKV + NWQ + 2 * NWKV + NWO);
    dim3 blk(256);

    if (ws_size >= need) {
        unsigned short* hb  = (unsigned short*)d_ws;
        unsigned short* qb  = hb + NHS;
        unsigned short* ab  = qb + NQ;
        unsigned short* kb  = ab + NQ;
        unsigned short* vb  = kb + NKV;
        unsigned short* vt  = vb + NKV;
        unsigned short* Wqb = vt + NKV;
        unsigned short* Wkb = Wqb + NWQ;
        unsigned short* Wvb = Wkb + NWKV;
        unsigned short* Wob = Wvb + NWKV;

        convert5<<<dim3(1024), blk, 0, stream>>>(
            hs, Wq, Wk, Wv, Wo, hb, Wqb, Wkb, Wvb, Wob,
            (int)(NHS / 4), (int)(NWQ / 4), (int)(NWKV / 4), (int)(NWKV / 4), (int)(NWO / 4));

        gemm_bb<true, true><<<dim3(32, 28), blk, 0, stream>>>(hb, Wqb, bq, qb, 3584, 3584);
        gemm_bb<true, true><<<dim3(32, 4),  blk, 0, stream>>>(hb, Wkb, bk, kb, 3584, 512);
        gemm_bb<true, true><<<dim3(32, 4),  blk, 0, stream>>>(hb, Wvb, bv, vb, 3584, 512);
        rope2<<<dim3(4096), blk, 0, stream>>>(qb, kb, cosp, sinp);
        transpose_v<<<dim3(64, 8), blk, 0, stream>>>(vb, vt);
        attn5<<<dim3(1792), blk, 0, stream>>>(qb, kb, vt, ab);
        gemm_bb<false, false><<<dim3(32, 28), blk, 0, stream>>>(ab, Wob, nullptr, out, 3584, 3584);
    } else {
        unsigned short* qb = (unsigned short*)d_ws;
        unsigned short* kb = qb + NQ;
        unsigned short* vb = kb + NKV;
        unsigned short* vt = vb + NKV;
        unsigned short* ab = vt + NKV;

        gemm_nt<false, true, true><<<dim3(32, 28), blk, 0, stream>>>(hs, Wq, bq, qb, 3584, 3584);
        gemm_nt<false, true, true><<<dim3(32, 4),  blk, 0, stream>>>(hs, Wk, bk, kb, 3584, 512);
        gemm_nt<false, true, true><<<dim3(32, 4),  blk, 0, stream>>>(hs, Wv, bv, vb, 3584, 512);
        rope2<<<dim3(4096), blk, 0, stream>>>(qb, kb, cosp, sinp);
        transpose_v<<<dim3(64, 8), blk, 0, stream>>>(vb, vt);
        attn5<<<dim3(1792), blk, 0, stream>>>(qb, kb, vt, ab);
        gemm_nt<true, false, false><<<dim3(32, 28), blk, 0, stream>>>(ab, Wo, nullptr, out, 3584, 3584);
    }
}

// Round 4
// 727.922 us; speedup vs baseline: 1.6673x; 1.1526x over previous
//
#include <hip/hip_runtime.h>

// ---------------------------------------------------------------------------
// Qwen2 attention forward: QKV proj + RoPE + causal GQA attention + O proj
// B=2 S=2048 HIDDEN=3584 NH=28 NKV=4 D=128
// ---------------------------------------------------------------------------

typedef __bf16 bf16x8 __attribute__((ext_vector_type(8)));
typedef float floatx4 __attribute__((ext_vector_type(4)));
typedef unsigned short ushort8v __attribute__((ext_vector_type(8)));
typedef unsigned short ushort4v __attribute__((ext_vector_type(4)));

__device__ __forceinline__ unsigned short f2bf(float f) {
    union { float f; unsigned int u; } v; v.f = f;
    return (unsigned short)((v.u + 0x7fffu + ((v.u >> 16) & 1u)) >> 16);
}
__device__ __forceinline__ float bf2f(unsigned short b) {
    union { unsigned int u; float f; } v; v.u = ((unsigned int)b) << 16;
    return v.f;
}
__device__ __forceinline__ floatx4 mfma16(bf16x8 a, bf16x8 b, floatx4 c) {
    return __builtin_amdgcn_mfma_f32_16x16x32_bf16(a, b, c, 0, 0, 0);
}
__device__ __forceinline__ bf16x8 ld8(const unsigned short* p) {
    ushort8v t = *(const ushort8v*)p;
    return __builtin_bit_cast(bf16x8, t);
}

// async global->LDS, 16B per lane; LDS dest = wave-uniform base + lane*16
#define GLL16(g, l) __builtin_amdgcn_global_load_lds( \
    (const __attribute__((address_space(1))) void*)(g), \
    (__attribute__((address_space(3))) void*)(l), 16, 0, 0)

// ---------------------------------------------------------------------------
// fp32 -> bf16 bulk convert of 5 arrays (vec4 granularity)
// ---------------------------------------------------------------------------
__global__ __launch_bounds__(256) void convert5(
    const float* __restrict__ s0, const float* __restrict__ s1,
    const float* __restrict__ s2, const float* __restrict__ s3,
    const float* __restrict__ s4,
    unsigned short* __restrict__ d0, unsigned short* __restrict__ d1,
    unsigned short* __restrict__ d2, unsigned short* __restrict__ d3,
    unsigned short* __restrict__ d4,
    int n0, int n1, int n2, int n3, int n4)
{
    int total = n0 + n1 + n2 + n3 + n4;
    for (int i = blockIdx.x * blockDim.x + threadIdx.x; i < total;
         i += gridDim.x * blockDim.x) {
        const float* s; unsigned short* d; int j = i;
        if (j < n0)      { s = s0; d = d0; }
        else { j -= n0; if (j < n1) { s = s1; d = d1; }
        else { j -= n1; if (j < n2) { s = s2; d = d2; }
        else { j -= n2; if (j < n3) { s = s3; d = d3; }
        else { j -= n3;   s = s4; d = d4; } } } }
        float4 v = ((const float4*)s)[j];
        ushort4v o;
        o[0] = f2bf(v.x); o[1] = f2bf(v.y); o[2] = f2bf(v.z); o[3] = f2bf(v.w);
        ((ushort4v*)d)[j] = o;
    }
}

// ---------------------------------------------------------------------------
// 256x256 deep-pipelined NT GEMM (T1+T2+T3+T4+T5), BK=64, 8 waves (2Mx4N),
// per-wave output 128x64 (8x4 16x16 frags). LDS 128KB: 2 dbuf x (A,B) 32KB
// XOR-swizzled tiles. Next K-tile staged via 8 GLL16 at iteration top, in
// flight across all 4 phases; single vmcnt(0)+barrier gate at tile boundary
// (loads are ~4 phases old there -> near-free). Raw s_barrier only (never
// __syncthreads: its vmcnt(0) would drain the prefetch queue).
// QKV=true: B is the concatenated [Wq;Wk;Wv] (N=4608), output routed per
// 256-block to qb/kb/vb with bias. QKV=false: plain fp32 out, N=3584.
// Grid 1D, bijective XCD swizzle (gridDim % 8 == 0), M-blocks = 16.
// ---------------------------------------------------------------------------
template<bool QKV>
__global__ __launch_bounds__(512, 2) void gemm256(
    const unsigned short* __restrict__ A, const unsigned short* __restrict__ B,
    const float* __restrict__ bqp, const float* __restrict__ bkp,
    const float* __restrict__ bvp,
    unsigned short* __restrict__ Cq, unsigned short* __restrict__ Ck,
    unsigned short* __restrict__ Cv, float* __restrict__ Cf,
    int K, int NT)
{
    __shared__ unsigned short As[2][256 * 64];
    __shared__ unsigned short Bs[2][256 * 64];

    const int tid = threadIdx.x, lane = tid & 63, w = tid >> 6;
    const int quad = lane >> 4, l16 = lane & 15;
    const int wm2 = w >> 2, wn4 = w & 3;

    // bijective XCD swizzle: 8 contiguous chunks of the (m,n) space per XCD
    const int cpx = gridDim.x >> 3;
    const int s = (blockIdx.x & 7) * cpx + (blockIdx.x >> 3);
    const int m0 = (s & 15) * 256, n0 = (s >> 4) * 256;

    const unsigned short* Ab = A + (size_t)m0 * K;
    const unsigned short* Bb = B + (size_t)n0 * K;

    // stage one 256x64 tile: 2048 16B-units, 4 GLL16/thread, linear LDS dest,
    // pre-swizzled global source: LDS[row][u] = G[row][u ^ (row&7)]
    auto stage = [&](const unsigned short* __restrict__ G, int kt,
                     unsigned short* lds) {
        const unsigned short* gb = G + (size_t)kt * 64;
        #pragma unroll
        for (int p = 0; p < 4; ++p) {
            int u = (w * 4 + p) * 64 + lane;
            int row = u >> 3, c = u & 7;
            GLL16(gb + (size_t)row * K + ((c ^ (row & 7)) * 8),
                  lds + (w * 4 + p) * 512);
        }
        asm volatile("" ::: "memory");
    };

    floatx4 acc[8][4] = {};

    stage(Ab, 0, &As[0][0]);
    stage(Bb, 0, &Bs[0][0]);
    asm volatile("s_waitcnt vmcnt(0)\n\ts_barrier" ::: "memory");

    for (int t = 0; t < NT; ++t) {
        const int buf = t & 1;
        if (t + 1 < NT) {
            stage(Ab, t + 1, &As[buf ^ 1][0]);
            stage(Bb, t + 1, &Bs[buf ^ 1][0]);
        }
        const unsigned short* Ap = &As[buf][0];
        const unsigned short* Bp = &Bs[buf][0];

        #pragma unroll
        for (int ks = 0; ks < 2; ++ks) {
            // A-frags for this 32-wide k-slice (reused across both N-halves)
            bf16x8 af[8];
            #pragma unroll
            for (int mf = 0; mf < 8; ++mf) {
                int row = wm2 * 128 + mf * 16 + l16;
                af[mf] = ld8(Ap + row * 64 + (((ks * 4 + quad) ^ (row & 7)) * 8));
            }
            #pragma unroll
            for (int nh = 0; nh < 2; ++nh) {
                bf16x8 bfr[2];
                #pragma unroll
                for (int nf = 0; nf < 2; ++nf) {
                    int row = wn4 * 64 + nh * 32 + nf * 16 + l16;
                    bfr[nf] = ld8(Bp + row * 64 + (((ks * 4 + quad) ^ (row & 7)) * 8));
                }
                asm volatile("s_barrier" ::: "memory");
                __builtin_amdgcn_s_setprio(1);
                #pragma unroll
                for (int mf = 0; mf < 8; ++mf) {
                    acc[mf][nh * 2 + 0] = mfma16(af[mf], bfr[0], acc[mf][nh * 2 + 0]);
                    acc[mf][nh * 2 + 1] = mfma16(af[mf], bfr[1], acc[mf][nh * 2 + 1]);
                }
                __builtin_amdgcn_s_setprio(0);
                asm volatile("s_barrier" ::: "memory");
            }
        }
        // gate: next tile's 8 stage ops (issued at this iteration's top) done
        asm volatile("s_waitcnt vmcnt(0)\n\ts_barrier" ::: "memory");
    }

    #pragma unroll
    for (int nf4 = 0; nf4 < 4; ++nf4) {
        int colg = n0 + wn4 * 64 + nf4 * 16 + l16;
        if (QKV) {
            unsigned short* Cp; const float* bp; int col, ldc;
            if (n0 < 3584)      { Cp = Cq; bp = bqp; col = colg;        ldc = 3584; }
            else if (n0 < 4096) { Cp = Ck; bp = bkp; col = colg - 3584; ldc = 512; }
            else                { Cp = Cv; bp = bvp; col = colg - 4096; ldc = 512; }
            float bb = bp[col];
            #pragma unroll
            for (int mf = 0; mf < 8; ++mf) {
                int rowg = m0 + wm2 * 128 + mf * 16 + quad * 4;
                #pragma unroll
                for (int r = 0; r < 4; ++r)
                    Cp[(size_t)(rowg + r) * ldc + col] = f2bf(acc[mf][nf4][r] + bb);
            }
        } else {
            #pragma unroll
            for (int mf = 0; mf < 8; ++mf) {
                int rowg = m0 + wm2 * 128 + mf * 16 + quad * 4;
                #pragma unroll
                for (int r = 0; r < 4; ++r)
                    Cf[(size_t)(rowg + r) * 3584 + colg] = acc[mf][nf4][r];
            }
        }
    }
}

// ---------------------------------------------------------------------------
// v1 fp32-staging GEMM (fallback path when workspace is small)
// ---------------------------------------------------------------------------
template<bool A_BF16, bool HAS_BIAS, bool OUT_BF16>
__global__ __launch_bounds__(256) void gemm_nt(
    const void* __restrict__ Ap, const float* __restrict__ Bp,
    const float* __restrict__ bias, void* __restrict__ Cp,
    int K, int ldc)
{
    __shared__ unsigned short As[128][40];
    __shared__ unsigned short Bs[128][40];

    const int tid = threadIdx.x, lane = tid & 63, w = tid >> 6;
    const int quad = lane >> 4, l16 = lane & 15;
    const int m0 = blockIdx.x * 128, n0 = blockIdx.y * 128;
    const int wm = (w & 1) * 64, wn = (w >> 1) * 64;

    floatx4 acc[4][4] = {};

    for (int k0 = 0; k0 < K; k0 += 32) {
        __syncthreads();
        if (A_BF16) {
            const unsigned short* Ab = (const unsigned short*)Ap;
            #pragma unroll
            for (int p = 0; p < 2; ++p) {
                int idx = tid + p * 256;
                int row = idx >> 2, seg = idx & 3;
                ushort8v v = *(const ushort8v*)(Ab + (size_t)(m0 + row) * K + k0 + seg * 8);
                *(ushort8v*)&As[row][seg * 8] = v;
            }
        } else {
            const float* Af = (const float*)Ap;
            #pragma unroll
            for (int p = 0; p < 4; ++p) {
                int idx = tid + p * 256;
                int row = idx >> 3, seg = idx & 7;
                const float4 v = *(const float4*)(Af + (size_t)(m0 + row) * K + k0 + seg * 4);
                ushort4v b;
                b[0] = f2bf(v.x); b[1] = f2bf(v.y); b[2] = f2bf(v.z); b[3] = f2bf(v.w);
                *(ushort4v*)&As[row][seg * 4] = b;
            }
        }
        #pragma unroll
        for (int p = 0; p < 4; ++p) {
            int idx = tid + p * 256;
            int row = idx >> 3, seg = idx & 7;
            const float4 v = *(const float4*)(Bp + (size_t)(n0 + row) * K + k0 + seg * 4);
            ushort4v b;
            b[0] = f2bf(v.x); b[1] = f2bf(v.y); b[2] = f2bf(v.z); b[3] = f2bf(v.w);
            *(ushort4v*)&Bs[row][seg * 4] = b;
        }
        __syncthreads();
        bf16x8 af[4], bv[4];
        #pragma unroll
        for (int i = 0; i < 4; ++i) af[i] = ld8(&As[wm + i * 16 + l16][quad * 8]);
        #pragma unroll
        for (int j = 0; j < 4; ++j) bv[j] = ld8(&Bs[wn + j * 16 + l16][quad * 8]);
        #pragma unroll
        for (int i = 0; i < 4; ++i)
            #pragma unroll
            for (int j = 0; j < 4; ++j)
                acc[i][j] = mfma16(af[i], bv[j], acc[i][j]);
    }

    #pragma unroll
    for (int j = 0; j < 4; ++j) {
        int col = n0 + wn + j * 16 + l16;
        float bb = HAS_BIAS ? bias[col] : 0.0f;
        #pragma unroll
        for (int i = 0; i < 4; ++i) {
            int row = m0 + wm + i * 16 + quad * 4;
            #pragma unroll
            for (int r = 0; r < 4; ++r) {
                float v = acc[i][j][r] + bb;
                if (OUT_BF16)
                    ((unsigned short*)Cp)[(size_t)(row + r) * ldc + col] = f2bf(v);
                else
                    ((float*)Cp)[(size_t)(row + r) * ldc + col] = v;
            }
        }
    }
}

// ---------------------------------------------------------------------------
// RoPE in place: one block per token, 32 head-slices (28 q + 4 k)
// ---------------------------------------------------------------------------
__global__ __launch_bounds__(256) void rope2(
    unsigned short* __restrict__ Q, unsigned short* __restrict__ K,
    const float* __restrict__ cosp, const float* __restrict__ sinp)
{
    const int tok = blockIdx.x, tid = threadIdx.x;
    __shared__ float cs[128], ss[128];
    if (tid < 128) {
        cs[tid] = cosp[(size_t)tok * 128 + tid];
        ss[tid] = sinp[(size_t)tok * 128 + tid];
    }
    __syncthreads();

    ushort8v x[2], x2[2];
    unsigned short* bases[2];
    int segs[2];
    #pragma unroll
    for (int p = 0; p < 2; ++p) {
        int chunk = tid + p * 256;              // 0..511
        int hh = chunk >> 4, seg = chunk & 15;
        unsigned short* base = (hh < 28)
            ? Q + (size_t)tok * 3584 + hh * 128
            : K + (size_t)tok * 512 + (hh - 28) * 128;
        bases[p] = base; segs[p] = seg;
        x[p]  = *(const ushort8v*)(base + seg * 8);
        x2[p] = *(const ushort8v*)(base + (seg ^ 8) * 8);
    }
    __syncthreads();   // all reads complete before any thread writes
    #pragma unroll
    for (int p = 0; p < 2; ++p) {
        int seg = segs[p];
        ushort8v y;
        #pragma unroll
        for (int j = 0; j < 8; ++j) {
            int d = seg * 8 + j;
            float xv = bf2f(x[p][j]);
            float rv = bf2f(x2[p][j]);
            float rot = (seg < 8) ? -rv : rv;
            y[j] = f2bf(xv * cs[d] + rot * ss[d]);
        }
        *(ushort8v*)(bases[p] + seg * 8) = y;
    }
}

// ---------------------------------------------------------------------------
// V transpose: vb[4096 tok][512 gd] -> vt[512 gd][4096 tok]
// ---------------------------------------------------------------------------
__global__ __launch_bounds__(256) void transpose_v(
    const unsigned short* __restrict__ vb, unsigned short* __restrict__ vt)
{
    __shared__ unsigned short Ts[64][68];
    const int t0 = blockIdx.x * 64, c0 = blockIdx.y * 64;
    const int tid = threadIdx.x;
    #pragma unroll
    for (int it = 0; it < 4; ++it) {
        int idx = tid + it * 256;
        int row = idx >> 4, seg = idx & 15;
        *(ushort4v*)&Ts[row][seg * 4] =
            *(const ushort4v*)(vb + (size_t)(t0 + row) * 512 + c0 + seg * 4);
    }
    __syncthreads();
    #pragma unroll
    for (int it = 0; it < 4; ++it) {
        int idx = tid + it * 256;
        int gd = idx >> 4, seg = idx & 15;
        ushort4v y;
        #pragma unroll
        for (int j = 0; j < 4; ++j) y[j] = Ts[seg * 4 + j][gd];
        *(ushort4v*)(vt + (size_t)(c0 + gd) * 4096 + t0 + seg * 4) = y;
    }
}

// ---------------------------------------------------------------------------
// Flash attention v5: K AND V both staged async into XOR-swizzled LDS,
// double-buffered, ONE vmcnt(0)+barrier per iter. Defer-max softmax.
// Grid: 1D 1792, XCD slice-pinned (bid&7), LPT (qt desc) inside each slice.
// ---------------------------------------------------------------------------
__global__ __launch_bounds__(256, 2) void attn5(
    const unsigned short* __restrict__ Q, const unsigned short* __restrict__ Kb,
    const unsigned short* __restrict__ Vt, unsigned short* __restrict__ O)
{
    const int bid   = blockIdx.x;
    const int slice = bid & 7;          // -> XCD via round-robin dispatch
    const int b     = slice & 1;
    const int kvh   = slice >> 1;
    const int j     = bid >> 3;         // 0..223 within slice
    const int qt    = 31 - (j / 7);     // LPT: heaviest q-tiles first
    const int h     = kvh * 7 + (j % 7);

    const int tid = threadIdx.x, lane = tid & 63, w = tid >> 6;
    const int quad = lane >> 4, l16 = lane & 15;

    __shared__ unsigned short Ks[2][64 * 128];   // [key][d], XOR-swizzled
    __shared__ unsigned short Vs[2][128 * 64];   // [d][key], XOR-swizzled
    __shared__ unsigned short Ps[64][72];        // per-wave-private rows

    // Q fragments in registers (A-layout), held for whole kernel (4 loads)
    bf16x8 aq[4];
    {
        const unsigned short* qp =
            Q + (size_t)(b * 2048 + qt * 64 + w * 16 + l16) * 3584 + h * 128 + quad * 8;
        #pragma unroll
        for (int ks = 0; ks < 4; ++ks) aq[ks] = ld8(qp + ks * 32);
    }

    const unsigned short* vbase = Vt + (size_t)kvh * 128 * 4096 + b * 2048;
    const unsigned short* kbase = Kb + (size_t)(b * 2048) * 512 + kvh * 128;

    auto stageK = [&](int kt, int buf) {
        const unsigned short* kt_base = kbase + (size_t)kt * 64 * 512;
        #pragma unroll
        for (int p = 0; p < 4; ++p) {
            int u = (w * 4 + p) * 64 + lane;     // 16B-unit index 0..1023
            int row = u >> 4, c16 = u & 15;
            GLL16(kt_base + (size_t)row * 512 + ((c16 ^ (row & 7)) * 8),
                  &Ks[buf][0] + (w * 4 + p) * 512);
        }
        asm volatile("" ::: "memory");
    };
    auto stageV = [&](int kt, int buf) {
        const unsigned short* vt_base = vbase + kt * 64;
        #pragma unroll
        for (int p = 0; p < 4; ++p) {
            int u = (w * 4 + p) * 64 + lane;     // 16B-unit index 0..1023
            int d = u >> 3, c16 = u & 7;
            GLL16(vt_base + (size_t)d * 4096 + ((c16 ^ (d & 7)) * 8),
                  &Vs[buf][0] + (w * 4 + p) * 512);
        }
        asm volatile("" ::: "memory");
    };

    stageK(0, 0);
    stageV(0, 0);

    floatx4 o[8] = {};
    float mrow[4], trow[4], lrow[4];
    const float cexp = 0.08838834764831845f * 1.4426950408889634f;
    const float thr_raw = 8.0f / cexp;
    #pragma unroll
    for (int r = 0; r < 4; ++r) {
        mrow[r] = -1e30f; trow[r] = -1e30f * cexp; lrow[r] = 0.f;
    }

    int cur = 0;
    for (int kt = 0; kt <= qt; ++kt) {
        // tile kt's 32 stage ops were issued one full iteration ago
        asm volatile("s_waitcnt vmcnt(0)\n\ts_barrier" ::: "memory");
        if (kt < qt) { stageK(kt + 1, cur ^ 1); stageV(kt + 1, cur ^ 1); }

        // ---- S = Q K^T from swizzled LDS ----
        floatx4 s[4] = {};
        __builtin_amdgcn_s_setprio(1);
        #pragma unroll
        for (int ks = 0; ks < 4; ++ks) {
            bf16x8 kf[4];
            #pragma unroll
            for (int n4 = 0; n4 < 4; ++n4) {
                int row = n4 * 16 + l16;
                kf[n4] = ld8(&Ks[cur][row * 128 + (((ks * 4 + quad) ^ (row & 7)) * 8)]);
            }
            #pragma unroll
            for (int n4 = 0; n4 < 4; ++n4)
                s[n4] = mfma16(aq[ks], kf[n4], s[n4]);
        }
        __builtin_amdgcn_s_setprio(0);

        // ---- defer-max softmax: speculative exp with old running max ----
        const bool diag = (kt == qt);
        float pv[4][4];
        int need = 0;
        #pragma unroll
        for (int r = 0; r < 4; ++r) {
            if (diag) {
                int qg = qt * 64 + w * 16 + quad * 4 + r;
                int kg = kt * 64 + l16;
                if (kg      > qg) s[0][r] = -1e30f;
                if (kg + 16 > qg) s[1][r] = -1e30f;
                if (kg + 32 > qg) s[2][r] = -1e30f;
                if (kg + 48 > qg) s[3][r] = -1e30f;
            }
            float mx = fmaxf(fmaxf(s[0][r], s[1][r]), fmaxf(s[2][r], s[3][r]));
            need |= (mx > mrow[r] + thr_raw) ? 1 : 0;
            pv[r][0] = __builtin_amdgcn_exp2f(fmaf(s[0][r], cexp, -trow[r]));
            pv[r][1] = __builtin_amdgcn_exp2f(fmaf(s[1][r], cexp, -trow[r]));
            pv[r][2] = __builtin_amdgcn_exp2f(fmaf(s[2][r], cexp, -trow[r]));
            pv[r][3] = __builtin_amdgcn_exp2f(fmaf(s[3][r], cexp, -trow[r]));
        }
        if (__any(need)) {                       // rare after kt==0
            #pragma unroll
            for (int r = 0; r < 4; ++r) {
                float mx = fmaxf(fmaxf(s[0][r], s[1][r]), fmaxf(s[2][r], s[3][r]));
                #pragma unroll
                for (int off = 1; off < 16; off <<= 1)
                    mx = fmaxf(mx, __shfl_xor(mx, off, 64));
                float mnew  = fmaxf(mrow[r], mx);
                float alpha = __builtin_amdgcn_exp2f((mrow[r] - mnew) * cexp);
                mrow[r] = mnew; trow[r] = mnew * cexp;
                lrow[r] *= alpha;
                #pragma unroll
                for (int d4 = 0; d4 < 8; ++d4) o[d4][r] *= alpha;
                pv[r][0] = __builtin_amdgcn_exp2f(fmaf(s[0][r], cexp, -trow[r]));
                pv[r][1] = __builtin_amdgcn_exp2f(fmaf(s[1][r], cexp, -trow[r]));
                pv[r][2] = __builtin_amdgcn_exp2f(fmaf(s[2][r], cexp, -trow[r]));
                pv[r][3] = __builtin_amdgcn_exp2f(fmaf(s[3][r], cexp, -trow[r]));
            }
        }
        #pragma unroll
        for (int r = 0; r < 4; ++r) {
            lrow[r] += pv[r][0] + pv[r][1] + pv[r][2] + pv[r][3];
            int prow = w * 16 + quad * 4 + r;
            Ps[prow][ 0 + l16] = f2bf(pv[r][0]);
            Ps[prow][16 + l16] = f2bf(pv[r][1]);
            Ps[prow][32 + l16] = f2bf(pv[r][2]);
            Ps[prow][48 + l16] = f2bf(pv[r][3]);
        }

        // ---- O += P V (V^T B-frags from swizzled LDS) ----
        __builtin_amdgcn_s_setprio(1);
        #pragma unroll
        for (int ks2 = 0; ks2 < 2; ++ks2) {
            bf16x8 ap = ld8(&Ps[w * 16 + l16][ks2 * 32 + quad * 8]);
            #pragma unroll
            for (int d4 = 0; d4 < 8; ++d4) {
                int d = d4 * 16 + l16;
                int sp = (ks2 * 4 + quad) ^ (d & 7);
                bf16x8 bv = ld8(&Vs[cur][d * 64 + sp * 8]);
                o[d4] = mfma16(ap, bv, o[d4]);
            }
        }
        __builtin_amdgcn_s_setprio(0);
        cur ^= 1;
    }

    // reduce per-lane partial row sums across the 16 lanes of each row (once)
    #pragma unroll
    for (int r = 0; r < 4; ++r) {
        float l = lrow[r];
        #pragma unroll
        for (int off = 1; off < 16; off <<= 1)
            l += __shfl_xor(l, off, 64);
        lrow[r] = 1.0f / l;
    }
    #pragma unroll
    for (int d4 = 0; d4 < 8; ++d4) {
        int col = h * 128 + d4 * 16 + l16;
        #pragma unroll
        for (int r = 0; r < 4; ++r) {
            int row = b * 2048 + qt * 64 + w * 16 + quad * 4 + r;
            O[(size_t)row * 3584 + col] = f2bf(o[d4][r] * lrow[r]);
        }
    }
}

// ---------------------------------------------------------------------------
extern "C" void kernel_launch(void* const* d_in, const int* in_sizes, int n_in,
                              void* d_out, int out_size, void* d_ws, size_t ws_size,
                              hipStream_t stream)
{
    (void)in_sizes; (void)n_in; (void)out_size;
    const float* hs   = (const float*)d_in[0];
    const float* cosp = (const float*)d_in[1];
    const float* sinp = (const float*)d_in[2];
    const float* Wq   = (const float*)d_in[3];
    const float* bq   = (const float*)d_in[4];
    const float* Wk   = (const float*)d_in[5];
    const float* bk   = (const float*)d_in[6];
    const float* Wv   = (const float*)d_in[7];
    const float* bv   = (const float*)d_in[8];
    const float* Wo   = (const float*)d_in[9];
    float* out = (float*)d_out;

    const size_t NHS = 14680064;   // 4096*3584
    const size_t NWQ = 12845056;   // 3584*3584
    const size_t NWKV = 1835008;   // 512*3584
    const size_t NWO = 12845056;
    const size_t NQ  = 14680064;
    const size_t NKV = 2097152;    // 4096*512

    const size_t need = 2 * (NHS + NQ + NQ + 3 * NKV + NWQ + 2 * NWKV + NWO);
    dim3 blk(256);

    if (ws_size >= need) {
        unsigned short* hb  = (unsigned short*)d_ws;
        unsigned short* qb  = hb + NHS;
        unsigned short* ab  = qb + NQ;
        unsigned short* kb  = ab + NQ;
        unsigned short* vb  = kb + NKV;
        unsigned short* vt  = vb + NKV;
        unsigned short* Wqb = vt + NKV;
        unsigned short* Wkb = Wqb + NWQ;   // contiguous after Wqb
        unsigned short* Wvb = Wkb + NWKV;  // contiguous after Wkb -> [Wq;Wk;Wv]
        unsigned short* Wob = Wvb + NWKV;

        convert5<<<dim3(1024), blk, 0, stream>>>(
            hs, Wq, Wk, Wv, Wo, hb, Wqb, Wkb, Wvb, Wob,
            (int)(NHS / 4), (int)(NWQ / 4), (int)(NWKV / 4), (int)(NWKV / 4), (int)(NWO / 4));

        // fused QKV projection: B = [Wq;Wk;Wv] (N=4608), grid 16x18 = 288
        gemm256<true><<<dim3(288), dim3(512), 0, stream>>>(
            hb, Wqb, bq, bk, bv, qb, kb, vb, nullptr, 3584, 56);
        rope2<<<dim3(4096), blk, 0, stream>>>(qb, kb, cosp, sinp);
        transpose_v<<<dim3(64, 8), blk, 0, stream>>>(vb, vt);
        attn5<<<dim3(1792), blk, 0, stream>>>(qb, kb, vt, ab);
        // O projection: grid 16x14 = 224
        gemm256<false><<<dim3(224), dim3(512), 0, stream>>>(
            ab, Wob, nullptr, nullptr, nullptr, nullptr, nullptr, nullptr, out, 3584, 56);
    } else {
        unsigned short* qb = (unsigned short*)d_ws;
        unsigned short* kb = qb + NQ;
        unsigned short* vb = kb + NKV;
        unsigned short* vt = vb + NKV;
        unsigned short* ab = vt + NKV;

        gemm_nt<false, true, true><<<dim3(32, 28), blk, 0, stream>>>(hs, Wq, bq, qb, 3584, 3584);
        gemm_nt<false, true, true><<<dim3(32, 4),  blk, 0, stream>>>(hs, Wk, bk, kb, 3584, 512);
        gemm_nt<false, true, true><<<dim3(32, 4),  blk, 0, stream>>>(hs, Wv, bv, vb, 3584, 512);
        rope2<<<dim3(4096), blk, 0, stream>>>(qb, kb, cosp, sinp);
        transpose_v<<<dim3(64, 8), blk, 0, stream>>>(vb, vt);
        attn5<<<dim3(1792), blk, 0, stream>>>(qb, kb, vt, ab);
        gemm_nt<true, false, false><<<dim3(32, 28), blk, 0, stream>>>(ab, Wo, nullptr, out, 3584, 3584);
    }
}